// Round 12
// baseline (1036.447 us; speedup 1.0000x reference)
//
#include <hip/hip_runtime.h>
#include <math.h>

#define DEVI __device__ __forceinline__
typedef float fv4 __attribute__((ext_vector_type(4)));
typedef float f32x4 __attribute__((ext_vector_type(4)));
typedef short bf16x8 __attribute__((ext_vector_type(8)));
typedef unsigned short us4 __attribute__((ext_vector_type(4)));

DEVI float sigm(float x){ return 1.f/(1.f+__expf(-x)); }
DEVI unsigned short f2bf(float f){
    unsigned int u = __float_as_uint(f);
    u = (u + 0x7FFFu + ((u >> 16) & 1u)) >> 16;
    return (unsigned short)u;
}
DEVI float bf2f(unsigned short u){ return __uint_as_float(((unsigned int)u)<<16); }

// ---- block-wide (256 thr) reduction of two sums --------------------------
DEVI void blockReduce2(float& s1, float& s2, float* red){
    #pragma unroll
    for (int m=1;m<64;m<<=1){ s1+=__shfl_xor(s1,m); s2+=__shfl_xor(s2,m); }
    const int w = threadIdx.x>>6;
    if ((threadIdx.x&63)==0){ red[w]=s1; red[8+w]=s2; }
    __syncthreads();
    s1 = red[0]+red[1]+red[2]+red[3];
    s2 = red[8]+red[9]+red[10]+red[11];
}

// ---- generic row LayerNorm (f32 out) -------------------------------------
__global__ __launch_bounds__(256) void ln_rows(const float* __restrict__ in,
                                               const float* __restrict__ g,
                                               const float* __restrict__ bt,
                                               float* __restrict__ out, int C){
    __shared__ float red[16];
    const size_t row = blockIdx.x;
    const float* x = in + row*(size_t)C;
    float s1=0.f, s2=0.f;
    for (int c=threadIdx.x; c<C; c+=256){ float v=x[c]; s1+=v; s2+=v*v; }
    blockReduce2(s1,s2,red);
    const float inv = 1.f/(float)C;
    const float mu = s1*inv;
    const float rs = rsqrtf(s2*inv - mu*mu + 1e-5f);
    float* o = out + row*(size_t)C;
    for (int c=threadIdx.x; c<C; c+=256){
        float y = (x[c]-mu)*rs;
        if (g)  y *= g[c];
        if (bt) y += bt[c];
        o[c] = y;
    }
}

// ---- LayerNorm with bf16 output (C=256) -----------------------------------
__global__ __launch_bounds__(256) void ln_rows_bf(const float* __restrict__ in,
                                                  const float* __restrict__ g,
                                                  const float* __restrict__ bt,
                                                  unsigned short* __restrict__ out){
    __shared__ float red[16];
    const size_t row = blockIdx.x;
    const int t = threadIdx.x;
    const float v = in[row*256 + t];
    float s1=v, s2=v*v;
    blockReduce2(s1,s2,red);
    const float mu = s1*(1.f/256.f);
    const float rs = rsqrtf(s2*(1.f/256.f) - mu*mu + 1e-5f);
    out[row*256 + t] = f2bf((v-mu)*rs*g[t] + bt[t]);
}

// ---- all weight casts+transposes in ONE launch ---------------------------
__global__ __launch_bounds__(256) void cast_all(
    const float* __restrict__ Wq, const float* __restrict__ Wkv,
    const float* __restrict__ Wg, const float* __restrict__ Wo,
    const float* __restrict__ W1, const float* __restrict__ W2,
    const float* __restrict__ Wb,
    unsigned short* __restrict__ wcatT, unsigned short* __restrict__ WoT,
    unsigned short* __restrict__ W1T, unsigned short* __restrict__ W2T,
    unsigned short* __restrict__ WbT)
{
    __shared__ unsigned short tile[64][65];
    const int z = blockIdx.z;
    const float* src; unsigned short* dst; int K, N;
    switch(z){
      case 0: src=Wq;  dst=wcatT;           K=256; N=256; break;
      case 1: src=Wkv; dst=wcatT+256*256;   K=256; N=512; break;
      case 2: src=Wg;  dst=wcatT+768*256;   K=256; N=256; break;
      case 3: src=Wo;  dst=WoT;             K=256; N=256; break;
      case 4: src=W1;  dst=W1T;             K=256; N=512; break;
      case 5: src=W2;  dst=W2T;             K=256; N=512; break;
      default: src=Wb; dst=WbT;             K=512; N=256; break;
    }
    const int nt = blockIdx.x*64, kt = blockIdx.y*64;
    if (nt >= N || kt >= K) return;
    const int t = threadIdx.x;
    const int c = t & 63, r0 = t >> 6;
    #pragma unroll 4
    for (int rr=r0; rr<64; rr+=4)
        tile[rr][c] = f2bf(src[(size_t)(kt+rr)*N + nt + c]);
    __syncthreads();
    #pragma unroll 4
    for (int rr=r0; rr<64; rr+=4)
        dst[(size_t)(nt+rr)*K + kt + c] = tile[c][rr];
}

// ---- K/V transpose: kT/vT[b][d][j] from qkvg ------------------------------
__global__ __launch_bounds__(256) void kvtrans(const float* __restrict__ qkvg,
                                               float* __restrict__ kT,
                                               float* __restrict__ vT){
    __shared__ float tile[64][65];
    const int t = threadIdx.x;
    const int jt = blockIdx.x*64, dt = blockIdx.y*64, b = blockIdx.z;
    const int c = t & 63, r0 = t >> 6;
    #pragma unroll 4
    for (int rr=r0; rr<64; rr+=4)
        tile[rr][c] = qkvg[(size_t)((b<<10)+jt+rr)*1024 + 256 + dt + c];
    __syncthreads();
    #pragma unroll 4
    for (int rr=r0; rr<64; rr+=4)
        kT[((size_t)(b*256 + dt + rr))*1024 + jt + c] = tile[c][rr];
    __syncthreads();
    #pragma unroll 4
    for (int rr=r0; rr<64; rr+=4)
        tile[rr][c] = qkvg[(size_t)((b<<10)+jt+rr)*1024 + 512 + dt + c];
    __syncthreads();
    #pragma unroll 4
    for (int rr=r0; rr<64; rr+=4)
        vT[((size_t)(b*256 + dt + rr))*1024 + jt + c] = tile[c][rr];
}

// ---- MFMA bf16 GEMM ------------------------------------------------------
template<int MODE>
__global__ __launch_bounds__(256) void mfma_gemm(
    const unsigned short* __restrict__ A, int lda,
    const unsigned short* __restrict__ Bt, int ldbt,
    float* __restrict__ C, int ldc,
    int K,
    const float* __restrict__ resid,
    const float* __restrict__ mask,
    const float* __restrict__ gsrc,
    const int* __restrict__ idxp)
{
    __shared__ unsigned short As[64*40];
    __shared__ unsigned short Bs[64*40];
    const int t = threadIdx.x;
    const int lane = t & 63, wave = t >> 6;
    const int wr = wave >> 1, wc = wave & 1;
    const int bm = blockIdx.x*64, bn = blockIdx.y*64;
    const int srow = t >> 2, sk = (t & 3) * 8;
    const int l15 = lane & 15, lk = (lane >> 4) * 8;
    f32x4 acc[2][2] = {};
    for (int kt = 0; kt < K; kt += 32){
        *(uint4*)&As[srow*40 + sk] = *(const uint4*)&A [(size_t)(bm+srow)*lda  + kt + sk];
        *(uint4*)&Bs[srow*40 + sk] = *(const uint4*)&Bt[(size_t)(bn+srow)*ldbt + kt + sk];
        __syncthreads();
        bf16x8 a0 = *(const bf16x8*)&As[(32*wr +  0 + l15)*40 + lk];
        bf16x8 a1 = *(const bf16x8*)&As[(32*wr + 16 + l15)*40 + lk];
        bf16x8 b0 = *(const bf16x8*)&Bs[(32*wc +  0 + l15)*40 + lk];
        bf16x8 b1 = *(const bf16x8*)&Bs[(32*wc + 16 + l15)*40 + lk];
        acc[0][0] = __builtin_amdgcn_mfma_f32_16x16x32_bf16(a0,b0,acc[0][0],0,0,0);
        acc[0][1] = __builtin_amdgcn_mfma_f32_16x16x32_bf16(a0,b1,acc[0][1],0,0,0);
        acc[1][0] = __builtin_amdgcn_mfma_f32_16x16x32_bf16(a1,b0,acc[1][0],0,0,0);
        acc[1][1] = __builtin_amdgcn_mfma_f32_16x16x32_bf16(a1,b1,acc[1][1],0,0,0);
        __syncthreads();
    }
    const int rbase = (lane >> 4) * 4;
    #pragma unroll
    for (int m=0;m<2;++m){
        #pragma unroll
        for (int r=0;r<4;++r){
            const int grow = bm + 32*wr + 16*m + rbase + r;
            #pragma unroll
            for (int n=0;n<2;++n){
                const int gcol = bn + 32*wc + 16*n + l15;
                float v = acc[m][n][r];
                if (MODE==0){
                    C[(size_t)grow*ldc + gcol] = v;
                } else if (MODE==1){
                    const float mi = mask[grow];
                    C[(size_t)grow*ldc + gcol] = resid[(size_t)grow*256 + gcol] + v*mi;
                } else {
                    const float mi = mask[grow];
                    const int id = idxp[grow];
                    const int bbi = grow >> 10;
                    const float cg = gsrc[((size_t)(bbi*256+id))*256 + gcol]*mi;
                    C[(size_t)grow*ldc + gcol] = resid[(size_t)grow*256 + gcol] + sigm(cg)*v*mi;
                }
            }
        }
    }
}

// ---- MFMA dual: bmid(bf16) = silu(A@W1) * (A@W2) ---------------------------
__global__ __launch_bounds__(256) void mfma_dual(
    const unsigned short* __restrict__ A, int lda,
    const unsigned short* __restrict__ B1t,
    const unsigned short* __restrict__ B2t, int ldbt,
    unsigned short* __restrict__ C, int ldc,
    int K)
{
    __shared__ unsigned short As[64*40];
    __shared__ unsigned short B1s[64*40];
    __shared__ unsigned short B2s[64*40];
    const int t = threadIdx.x;
    const int lane = t & 63, wave = t >> 6;
    const int wr = wave >> 1, wc = wave & 1;
    const int bm = blockIdx.x*64, bn = blockIdx.y*64;
    const int srow = t >> 2, sk = (t & 3) * 8;
    const int l15 = lane & 15, lk = (lane >> 4) * 8;
    f32x4 acc1[2][2] = {};
    f32x4 acc2[2][2] = {};
    for (int kt = 0; kt < K; kt += 32){
        *(uint4*)&As [srow*40 + sk] = *(const uint4*)&A  [(size_t)(bm+srow)*lda  + kt + sk];
        *(uint4*)&B1s[srow*40 + sk] = *(const uint4*)&B1t[(size_t)(bn+srow)*ldbt + kt + sk];
        *(uint4*)&B2s[srow*40 + sk] = *(const uint4*)&B2t[(size_t)(bn+srow)*ldbt + kt + sk];
        __syncthreads();
        bf16x8 a0 = *(const bf16x8*)&As[(32*wr +  0 + l15)*40 + lk];
        bf16x8 a1 = *(const bf16x8*)&As[(32*wr + 16 + l15)*40 + lk];
        bf16x8 p0 = *(const bf16x8*)&B1s[(32*wc +  0 + l15)*40 + lk];
        bf16x8 p1 = *(const bf16x8*)&B1s[(32*wc + 16 + l15)*40 + lk];
        bf16x8 q0 = *(const bf16x8*)&B2s[(32*wc +  0 + l15)*40 + lk];
        bf16x8 q1 = *(const bf16x8*)&B2s[(32*wc + 16 + l15)*40 + lk];
        acc1[0][0] = __builtin_amdgcn_mfma_f32_16x16x32_bf16(a0,p0,acc1[0][0],0,0,0);
        acc1[0][1] = __builtin_amdgcn_mfma_f32_16x16x32_bf16(a0,p1,acc1[0][1],0,0,0);
        acc1[1][0] = __builtin_amdgcn_mfma_f32_16x16x32_bf16(a1,p0,acc1[1][0],0,0,0);
        acc1[1][1] = __builtin_amdgcn_mfma_f32_16x16x32_bf16(a1,p1,acc1[1][1],0,0,0);
        acc2[0][0] = __builtin_amdgcn_mfma_f32_16x16x32_bf16(a0,q0,acc2[0][0],0,0,0);
        acc2[0][1] = __builtin_amdgcn_mfma_f32_16x16x32_bf16(a0,q1,acc2[0][1],0,0,0);
        acc2[1][0] = __builtin_amdgcn_mfma_f32_16x16x32_bf16(a1,q0,acc2[1][0],0,0,0);
        acc2[1][1] = __builtin_amdgcn_mfma_f32_16x16x32_bf16(a1,q1,acc2[1][1],0,0,0);
        __syncthreads();
    }
    const int rbase = (lane >> 4) * 4;
    #pragma unroll
    for (int m=0;m<2;++m){
        #pragma unroll
        for (int r=0;r<4;++r){
            const int grow = bm + 32*wr + 16*m + rbase + r;
            #pragma unroll
            for (int n=0;n<2;++n){
                const int gcol = bn + 32*wc + 16*n + l15;
                const float u1 = acc1[m][n][r];
                C[(size_t)grow*ldc + gcol] = f2bf(u1*sigm(u1)*acc2[m][n][r]);
            }
        }
    }
}

// ---- 3 small conditioning GEMMs fused into one launch (z selects) ---------
// z=0: c1res = cn@Wc1 + bc1   z=1: cbres = cn@Wcn   z=2: cgres = s_@Wc2 + bc2
__global__ __launch_bounds__(256) void gemm3(
    const float* __restrict__ cn, const float* __restrict__ s_,
    const float* __restrict__ Wc1, const float* __restrict__ Wcn,
    const float* __restrict__ Wc2,
    const float* __restrict__ bc1, const float* __restrict__ bc2,
    float* __restrict__ c1res, float* __restrict__ cbres,
    float* __restrict__ cgres)
{
    const int z = blockIdx.z;
    const float* A    = (z==2) ? s_  : cn;
    const float* B    = (z==0) ? Wc1 : (z==1) ? Wcn : Wc2;
    const float* bias = (z==0) ? bc1 : (z==2) ? bc2 : nullptr;
    float* C          = (z==0) ? c1res : (z==1) ? cbres : cgres;
    const int lda = 384, ldb = 256, ldc = 256, K = 384;
    __shared__ float As[16][68];
    __shared__ float Bs[16][68];
    const int t = threadIdx.x;
    const int tx = t & 15, ty = t >> 4;
    const int bm = blockIdx.x * 64, bn = blockIdx.y * 64;
    const int am = t >> 2, akq = (t & 3) * 4;
    const int bk = t >> 4, bnq = (t & 15) * 4;
    float acc[4][4] = {};
    for (int kt = 0; kt < K; kt += 16) {
        const float4 va = *(const float4*)&A[(size_t)(bm+am)*lda + kt + akq];
        const float4 vb = *(const float4*)&B[(size_t)(kt+bk)*ldb + bn + bnq];
        As[akq+0][am]=va.x; As[akq+1][am]=va.y; As[akq+2][am]=va.z; As[akq+3][am]=va.w;
        *(float4*)&Bs[bk][bnq] = vb;
        __syncthreads();
        #pragma unroll
        for (int kk=0; kk<16; ++kk){
            const float4 af = *(const float4*)&As[kk][ty*4];
            const float4 bf = *(const float4*)&Bs[kk][tx*4];
            acc[0][0]+=af.x*bf.x; acc[0][1]+=af.x*bf.y; acc[0][2]+=af.x*bf.z; acc[0][3]+=af.x*bf.w;
            acc[1][0]+=af.y*bf.x; acc[1][1]+=af.y*bf.y; acc[1][2]+=af.y*bf.z; acc[1][3]+=af.y*bf.w;
            acc[2][0]+=af.z*bf.x; acc[2][1]+=af.z*bf.y; acc[2][2]+=af.z*bf.z; acc[2][3]+=af.z*bf.w;
            acc[3][0]+=af.w*bf.x; acc[3][1]+=af.w*bf.y; acc[3][2]+=af.w*bf.z; acc[3][3]+=af.w*bf.w;
        }
        __syncthreads();
    }
    #pragma unroll
    for (int i=0;i<4;++i){
        const int m = bm + ty*4 + i;
        #pragma unroll
        for (int jj=0;jj<4;++jj){
            const int n = bn + tx*4 + jj;
            float v = acc[i][jj];
            if (bias) v += bias[n];
            C[(size_t)m*ldc+n] = v;
        }
    }
}

// ---- pair-bias precompute (bf16 out) --------------------------------------
__global__ __launch_bounds__(256,6) void pb_kernel(
    const float* __restrict__ fp,
    const float* __restrict__ lnzg, const float* __restrict__ lnzb,
    const float* __restrict__ wbias,
    const float* __restrict__ mask,
    unsigned short* __restrict__ pb)
{
    __shared__ unsigned short S[8][1040];
    __shared__ float maskS[1024];
    const int t = threadIdx.x;
    const int bi = blockIdx.x;
    const int b = bi >> 10, i = bi & 1023;
    const int l = t & 15, grp = t >> 4;

    float wg[4], wb_[4];
    fv4 w0[4], w1[4];
    #pragma unroll
    for (int cc=0; cc<4; ++cc){
        const int c = 4*l + cc;
        wg[cc] = lnzg[c]; wb_[cc] = lnzb[c];
        w0[cc] = *(const fv4*)&wbias[c*8];
        w1[cc] = *(const fv4*)&wbias[c*8+4];
    }
    *(fv4*)&maskS[t*4] = ((const fv4*)(mask + (b<<10)))[t];
    __syncthreads();
    const float mi = mask[bi];

    const fv4* fpv = (const fv4*)(fp + (size_t)bi*65536);
    fv4 c0 = fpv[(size_t)grp*16 + l];
    fv4 c1 = fpv[(size_t)(grp+16)*16 + l];
    #pragma unroll 1
    for (int jt=0; jt<1024; jt+=32){
        const fv4 f0=c0, f1=c1;
        if (jt+32 < 1024){
            c0 = fpv[(size_t)(jt+32+grp)*16 + l];
            c1 = fpv[(size_t)(jt+48+grp)*16 + l];
        }
        #pragma unroll
        for (int half=0; half<2; ++half){
            const fv4 f = half ? f1 : f0;
            const int j = jt + 16*half + grp;
            float s1 = f.x+f.y+f.z+f.w;
            float s2 = f.x*f.x+f.y*f.y+f.z*f.z+f.w*f.w;
            #pragma unroll
            for (int m=1;m<16;m<<=1){ s1 += __shfl_xor(s1,m); s2 += __shfl_xor(s2,m); }
            const float mu = s1*(1.f/64.f);
            const float rs = rsqrtf(s2*(1.f/64.f) - mu*mu + 1e-5f);
            float lnv[4];
            lnv[0]=(f.x-mu)*rs*wg[0]+wb_[0];
            lnv[1]=(f.y-mu)*rs*wg[1]+wb_[1];
            lnv[2]=(f.z-mu)*rs*wg[2]+wb_[2];
            lnv[3]=(f.w-mu)*rs*wg[3]+wb_[3];
            float pv[8] = {};
            #pragma unroll
            for (int cc=0;cc<4;++cc){
                pv[0]+=lnv[cc]*w0[cc].x; pv[1]+=lnv[cc]*w0[cc].y;
                pv[2]+=lnv[cc]*w0[cc].z; pv[3]+=lnv[cc]*w0[cc].w;
                pv[4]+=lnv[cc]*w1[cc].x; pv[5]+=lnv[cc]*w1[cc].y;
                pv[6]+=lnv[cc]*w1[cc].z; pv[7]+=lnv[cc]*w1[cc].w;
            }
            {
                const bool b8 = (l & 8);
                #pragma unroll
                for (int k=0;k<4;++k){
                    const float a = b8 ? pv[k] : pv[k+4];
                    const float r = __shfl_xor(a, 8);
                    pv[k] = (b8 ? pv[k+4] : pv[k]) + r;
                }
                const bool b4 = (l & 4);
                #pragma unroll
                for (int k=0;k<2;++k){
                    const float a = b4 ? pv[k] : pv[k+2];
                    const float r = __shfl_xor(a, 4);
                    pv[k] = (b4 ? pv[k+2] : pv[k]) + r;
                }
                const bool b2 = (l & 2);
                {
                    const float a = b2 ? pv[0] : pv[1];
                    const float r = __shfl_xor(a, 2);
                    pv[0] = (b2 ? pv[1] : pv[0]) + r;
                }
                pv[0] += __shfl_xor(pv[0], 1);
            }
            if ((l & 1) == 0){
                const float mterm = (mi*maskS[j]-1.f)*100000.f;
                S[(l>>1)][j] = f2bf(pv[0] + mterm);
            }
        }
    }
    __syncthreads();
    #pragma unroll 1
    for (int k=0;k<8;++k){
        const int j4 = (t & 255) * 4;
        const us4 v = *(const us4*)&S[k][j4];
        *(us4*)&pb[(((size_t)(b*8+k))*1024 + i)*1024 + j4] = v;
    }
}

// ---- attention v4: 8 rows x 1 head per block; K/V in LDS; P IN REGISTERS --
// Lane jl owns j = {tile*128 + jl*4 + k}. No S array: QK^T accumulates p[8][4]
// in VGPRs (pb added from global), softmax is register+shfl only, PV consumes
// p directly. LDS = KV tile (16.9KB) + qs only.
__global__ __launch_bounds__(256,3) void attn_tile(
    const float* __restrict__ qkvg,
    const float* __restrict__ kT,
    const float* __restrict__ vT,
    const unsigned short* __restrict__ pb,
    unsigned short* __restrict__ og)
{
    __shared__ float KV[32][132];
    __shared__ float qs[8][33];
    const int t = threadIdx.x;
    const int it = blockIdx.x, h = blockIdx.y, b = blockIdx.z;
    const int i0 = it*8;
    const int r = t >> 5, jl = t & 31;
    const int srow = t >> 3, sc0 = t & 7;

    qs[r][jl] = qkvg[((size_t)(b*1024 + i0 + r))*1024 + h*32 + jl];

    const float* kbase = kT + ((size_t)b*256 + h*32)*1024 + (size_t)srow*1024;
    const float* vbase = vT + ((size_t)b*256 + h*32)*1024 + (size_t)srow*1024;
    fv4 pf0 = *(const fv4*)&kbase[0*32 + sc0*4];
    fv4 pf1 = *(const fv4*)&kbase[1*32 + sc0*4];
    fv4 pf2 = *(const fv4*)&kbase[2*32 + sc0*4];
    fv4 pf3 = *(const fv4*)&kbase[3*32 + sc0*4];
    __syncthreads();                         // qs visible to all
    float q[32];
    #pragma unroll
    for (int d=0; d<32; ++d) q[d] = qs[r][d];
    const float scale = 0.17677669529663687f;
    const unsigned short* pbr = pb + (((size_t)(b*8+h))*1024 + i0 + r)*1024;

    float p[8][4];

    // ---- Phase A: QK^T over 8 K-tiles; p accumulated in registers ---------
    #pragma unroll
    for (int tile=0; tile<8; ++tile){
        __syncthreads();                     // prev tile fully consumed
        *(fv4*)&KV[srow][0*32 + sc0*4] = pf0;
        *(fv4*)&KV[srow][1*32 + sc0*4] = pf1;
        *(fv4*)&KV[srow][2*32 + sc0*4] = pf2;
        *(fv4*)&KV[srow][3*32 + sc0*4] = pf3;
        if (tile < 7){
            const float* nb = kbase + (tile+1)*128;
            pf0 = *(const fv4*)&nb[0*32 + sc0*4];
            pf1 = *(const fv4*)&nb[1*32 + sc0*4];
            pf2 = *(const fv4*)&nb[2*32 + sc0*4];
            pf3 = *(const fv4*)&nb[3*32 + sc0*4];
        } else {
            pf0 = *(const fv4*)&vbase[0*32 + sc0*4];   // V tile 0
            pf1 = *(const fv4*)&vbase[1*32 + sc0*4];
            pf2 = *(const fv4*)&vbase[2*32 + sc0*4];
            pf3 = *(const fv4*)&vbase[3*32 + sc0*4];
        }
        __syncthreads();                     // tile ready
        const us4 pbv = *(const us4*)&pbr[tile*128 + jl*4];
        float a0=0.f, a1=0.f, a2=0.f, a3=0.f;
        #pragma unroll
        for (int d=0; d<32; ++d){
            const fv4 kv = *(const fv4*)&KV[d][jl*4];
            a0 += q[d]*kv.x; a1 += q[d]*kv.y; a2 += q[d]*kv.z; a3 += q[d]*kv.w;
        }
        p[tile][0] = a0*scale + bf2f(pbv.x);
        p[tile][1] = a1*scale + bf2f(pbv.y);
        p[tile][2] = a2*scale + bf2f(pbv.z);
        p[tile][3] = a3*scale + bf2f(pbv.w);
    }

    // ---- Phase B: softmax entirely in registers (no LDS, no barrier) ------
    float mx = -3.4e38f;
    #pragma unroll
    for (int tt=0; tt<8; ++tt)
        mx = fmaxf(mx, fmaxf(fmaxf(p[tt][0],p[tt][1]), fmaxf(p[tt][2],p[tt][3])));
    #pragma unroll
    for (int off=16; off>0; off>>=1) mx = fmaxf(mx, __shfl_xor(mx, off, 32));
    float sum = 0.f;
    #pragma unroll
    for (int tt=0; tt<8; ++tt){
        p[tt][0] = __expf(p[tt][0]-mx);
        p[tt][1] = __expf(p[tt][1]-mx);
        p[tt][2] = __expf(p[tt][2]-mx);
        p[tt][3] = __expf(p[tt][3]-mx);
        sum += p[tt][0]+p[tt][1]+p[tt][2]+p[tt][3];
    }
    #pragma unroll
    for (int off=16; off>0; off>>=1) sum += __shfl_xor(sum, off, 32);
    const float inv = 1.f/sum;

    // ---- Phase C: PV over 8 V-tiles ---------------------------------------
    float acc[32];
    #pragma unroll
    for (int d=0; d<32; ++d) acc[d] = 0.f;
    #pragma unroll
    for (int tile=0; tile<8; ++tile){
        __syncthreads();                     // all groups done with prev KV
        *(fv4*)&KV[srow][0*32 + sc0*4] = pf0;
        *(fv4*)&KV[srow][1*32 + sc0*4] = pf1;
        *(fv4*)&KV[srow][2*32 + sc0*4] = pf2;
        *(fv4*)&KV[srow][3*32 + sc0*4] = pf3;
        if (tile < 7){
            const float* nb = vbase + (tile+1)*128;
            pf0 = *(const fv4*)&nb[0*32 + sc0*4];
            pf1 = *(const fv4*)&nb[1*32 + sc0*4];
            pf2 = *(const fv4*)&nb[2*32 + sc0*4];
            pf3 = *(const fv4*)&nb[3*32 + sc0*4];
        }
        __syncthreads();                     // tile ready
        #pragma unroll
        for (int d=0; d<32; ++d){
            const fv4 vv = *(const fv4*)&KV[d][jl*4];
            acc[d] += p[tile][0]*vv.x + p[tile][1]*vv.y
                    + p[tile][2]*vv.z + p[tile][3]*vv.w;
        }
    }

    // ---- reduce-scatter across 32 lanes -> lane jl holds o[d=jl] ----------
    {
        const bool c16 = jl & 16;
        #pragma unroll
        for (int k=0;k<16;++k){
            const float a = c16 ? acc[k] : acc[k+16];
            const float rr = __shfl_xor(a, 16);
            acc[k] = (c16 ? acc[k+16] : acc[k]) + rr;
        }
        const bool c8 = jl & 8;
        #pragma unroll
        for (int k=0;k<8;++k){
            const float a = c8 ? acc[k] : acc[k+8];
            const float rr = __shfl_xor(a, 8);
            acc[k] = (c8 ? acc[k+8] : acc[k]) + rr;
        }
        const bool c4 = jl & 4;
        #pragma unroll
        for (int k=0;k<4;++k){
            const float a = c4 ? acc[k] : acc[k+4];
            const float rr = __shfl_xor(a, 4);
            acc[k] = (c4 ? acc[k+4] : acc[k]) + rr;
        }
        const bool c2 = jl & 2;
        #pragma unroll
        for (int k=0;k<2;++k){
            const float a = c2 ? acc[k] : acc[k+2];
            const float rr = __shfl_xor(a, 2);
            acc[k] = (c2 ? acc[k+2] : acc[k]) + rr;
        }
        const bool c1 = jl & 1;
        {
            const float a = c1 ? acc[0] : acc[1];
            const float rr = __shfl_xor(a, 1);
            acc[0] = (c1 ? acc[1] : acc[0]) + rr;
        }
    }
    const int row = b*1024 + i0 + r;
    const float gpre = qkvg[(size_t)row*1024 + 768 + h*32 + jl];
    og[(size_t)row*256 + h*32 + jl] = f2bf(acc[0]*inv*sigm(gpre));
}

// ---- sa = LN(rig)*sigmoid(cond_gate) + cond_bias  (bf16 out) --------------
__global__ __launch_bounds__(256) void sa_kernel(
    const float* __restrict__ rig,
    const float* __restrict__ c1res,
    const float* __restrict__ cbres,
    const int* __restrict__ idxp,
    const float* __restrict__ mask,
    unsigned short* __restrict__ sa)
{
    __shared__ float red[16];
    const int m = blockIdx.x;
    const int t = threadIdx.x;
    const float v = rig[(size_t)m*256 + t];
    float s1 = v, s2 = v*v;
    blockReduce2(s1,s2,red);
    const float mu = s1*(1.f/256.f);
    const float rs = rsqrtf(s2*(1.f/256.f) - mu*mu + 1e-5f);
    const float sn = (v-mu)*rs;
    const float mi = mask[m];
    const int id = idxp[m];
    const int b = m >> 10;
    const size_t go = ((size_t)(b*256+id))*256 + t;
    const float cgate = c1res[go]*mi;
    const float cb    = cbres[go]*mi;
    sa[(size_t)m*256+t] = f2bf(sn*sigm(cgate) + cb);
}

extern "C" void kernel_launch(void* const* d_in, const int* in_sizes, int n_in,
                              void* d_out, int out_size, void* d_ws, size_t ws_size,
                              hipStream_t stream)
{
    (void)in_sizes; (void)n_in; (void)out_size; (void)ws_size;
    const float* s_     = (const float*)d_in[0];
    const float* rigids = (const float*)d_in[1];
    const float* fp     = (const float*)d_in[2];
    const float* maskp  = (const float*)d_in[3];
    const int*   idxp   = (const int*)d_in[4];
    const float* ln_g   = (const float*)d_in[5];
    const float* ln_b   = (const float*)d_in[6];
    const float* Wq     = (const float*)d_in[7];
    const float* Wkv    = (const float*)d_in[8];
    const float* lnz_g  = (const float*)d_in[9];
    const float* lnz_b  = (const float*)d_in[10];
    const float* Wbias  = (const float*)d_in[11];
    const float* Wg     = (const float*)d_in[12];
    const float* Wo     = (const float*)d_in[13];
    const float* lncond = (const float*)d_in[14];
    const float* Wc1    = (const float*)d_in[15];
    const float* bc1    = (const float*)d_in[16];
    const float* Wcn    = (const float*)d_in[17];
    const float* W1     = (const float*)d_in[18];
    const float* W2     = (const float*)d_in[19];
    const float* Wc2    = (const float*)d_in[20];
    const float* bc2    = (const float*)d_in[21];
    const float* Wb     = (const float*)d_in[22];
    float* out = (float*)d_out;

    float* ws    = (float*)d_ws;
    float* qkvg  = ws;                  // 2048*1024 f32
    float* rig   = qkvg  + 2097152;     // 2048*256
    float* cn    = rig   + 524288;      // 512*384
    float* c1res = cn    + 196608;      // 512*256
    float* cbres = c1res + 131072;      // 512*256
    float* cgres = cbres + 131072;      // 512*256
    float* kT    = cgres + 131072;      // 2*256*1024
    float* vT    = kT    + 524288;      // 2*256*1024
    float* bend  = vT    + 524288;
    unsigned short* xbf    = (unsigned short*)bend;        // 2048*256
    unsigned short* ogbf   = xbf    + 524288;              // 2048*256
    unsigned short* sabf   = ogbf   + 524288;              // 2048*256
    unsigned short* bmidbf = sabf   + 524288;              // 2048*512
    unsigned short* wcatT  = bmidbf + 1048576;             // 1024*256
    unsigned short* WoT    = wcatT  + 262144;              // 256*256
    unsigned short* W1T    = WoT    + 65536;               // 512*256
    unsigned short* W2T    = W1T    + 131072;              // 512*256
    unsigned short* WbT    = W2T    + 131072;              // 256*512
    unsigned short* pbbf   = WbT    + 131072;              // 32 MB bf16

    pb_kernel<<<2048,256,0,stream>>>(fp, lnz_g, lnz_b, Wbias, maskp, pbbf);
    cast_all<<<dim3(8,8,7),256,0,stream>>>(Wq, Wkv, Wg, Wo, W1, W2, Wb,
                                           wcatT, WoT, W1T, W2T, WbT);
    ln_rows_bf<<<2048,256,0,stream>>>(rigids, ln_g, ln_b, xbf);
    mfma_gemm<0><<<dim3(32,16),256,0,stream>>>(xbf,256, wcatT,256, qkvg,1024, 256, nullptr,nullptr,nullptr,nullptr);
    kvtrans<<<dim3(16,4,2),256,0,stream>>>(qkvg, kT, vT);
    attn_tile<<<dim3(128,8,2),256,0,stream>>>(qkvg, kT, vT, pbbf, ogbf);
    mfma_gemm<1><<<dim3(32,4),256,0,stream>>>(ogbf,256, WoT,256, rig,256, 256, rigids, maskp, nullptr,nullptr);
    ln_rows<<<512,256,0,stream>>>(s_, lncond, nullptr, cn, 384);
    gemm3<<<dim3(8,4,3),256,0,stream>>>(cn, s_, Wc1, Wcn, Wc2, bc1, bc2, c1res, cbres, cgres);
    sa_kernel<<<2048,256,0,stream>>>(rig, c1res, cbres, idxp, maskp, sabf);
    mfma_dual<<<dim3(32,8),256,0,stream>>>(sabf,256, W1T, W2T,256, bmidbf,512, 256);
    mfma_gemm<2><<<dim3(32,4),256,0,stream>>>(bmidbf,512, WbT,512, out,256, 512, rig, maskp, cgres, idxp);
}

// Round 13
// 289.260 us; speedup vs baseline: 3.5831x; 3.5831x over previous
//
#include <hip/hip_runtime.h>
#include <math.h>

#define DEVI __device__ __forceinline__
typedef float fv4 __attribute__((ext_vector_type(4)));
typedef float f32x4 __attribute__((ext_vector_type(4)));
typedef short bf16x8 __attribute__((ext_vector_type(8)));
typedef unsigned short us4 __attribute__((ext_vector_type(4)));

DEVI float sigm(float x){ return 1.f/(1.f+__expf(-x)); }
DEVI unsigned short f2bf(float f){
    unsigned int u = __float_as_uint(f);
    u = (u + 0x7FFFu + ((u >> 16) & 1u)) >> 16;
    return (unsigned short)u;
}
DEVI float bf2f(unsigned short u){ return __uint_as_float(((unsigned int)u)<<16); }

// ---- block-wide (256 thr) reduction of two sums --------------------------
DEVI void blockReduce2(float& s1, float& s2, float* red){
    #pragma unroll
    for (int m=1;m<64;m<<=1){ s1+=__shfl_xor(s1,m); s2+=__shfl_xor(s2,m); }
    const int w = threadIdx.x>>6;
    if ((threadIdx.x&63)==0){ red[w]=s1; red[8+w]=s2; }
    __syncthreads();
    s1 = red[0]+red[1]+red[2]+red[3];
    s2 = red[8]+red[9]+red[10]+red[11];
}

// ---- generic row LayerNorm (f32 out) -------------------------------------
__global__ __launch_bounds__(256) void ln_rows(const float* __restrict__ in,
                                               const float* __restrict__ g,
                                               const float* __restrict__ bt,
                                               float* __restrict__ out, int C){
    __shared__ float red[16];
    const size_t row = blockIdx.x;
    const float* x = in + row*(size_t)C;
    float s1=0.f, s2=0.f;
    for (int c=threadIdx.x; c<C; c+=256){ float v=x[c]; s1+=v; s2+=v*v; }
    blockReduce2(s1,s2,red);
    const float inv = 1.f/(float)C;
    const float mu = s1*inv;
    const float rs = rsqrtf(s2*inv - mu*mu + 1e-5f);
    float* o = out + row*(size_t)C;
    for (int c=threadIdx.x; c<C; c+=256){
        float y = (x[c]-mu)*rs;
        if (g)  y *= g[c];
        if (bt) y += bt[c];
        o[c] = y;
    }
}

// ---- LayerNorm with bf16 output (C=256) -----------------------------------
__global__ __launch_bounds__(256) void ln_rows_bf(const float* __restrict__ in,
                                                  const float* __restrict__ g,
                                                  const float* __restrict__ bt,
                                                  unsigned short* __restrict__ out){
    __shared__ float red[16];
    const size_t row = blockIdx.x;
    const int t = threadIdx.x;
    const float v = in[row*256 + t];
    float s1=v, s2=v*v;
    blockReduce2(s1,s2,red);
    const float mu = s1*(1.f/256.f);
    const float rs = rsqrtf(s2*(1.f/256.f) - mu*mu + 1e-5f);
    out[row*256 + t] = f2bf((v-mu)*rs*g[t] + bt[t]);
}

// ---- all weight casts+transposes in ONE launch ---------------------------
__global__ __launch_bounds__(256) void cast_all(
    const float* __restrict__ Wq, const float* __restrict__ Wkv,
    const float* __restrict__ Wg, const float* __restrict__ Wo,
    const float* __restrict__ W1, const float* __restrict__ W2,
    const float* __restrict__ Wb,
    unsigned short* __restrict__ wcatT, unsigned short* __restrict__ WoT,
    unsigned short* __restrict__ W1T, unsigned short* __restrict__ W2T,
    unsigned short* __restrict__ WbT)
{
    __shared__ unsigned short tile[64][65];
    const int z = blockIdx.z;
    const float* src; unsigned short* dst; int K, N;
    switch(z){
      case 0: src=Wq;  dst=wcatT;           K=256; N=256; break;
      case 1: src=Wkv; dst=wcatT+256*256;   K=256; N=512; break;
      case 2: src=Wg;  dst=wcatT+768*256;   K=256; N=256; break;
      case 3: src=Wo;  dst=WoT;             K=256; N=256; break;
      case 4: src=W1;  dst=W1T;             K=256; N=512; break;
      case 5: src=W2;  dst=W2T;             K=256; N=512; break;
      default: src=Wb; dst=WbT;             K=512; N=256; break;
    }
    const int nt = blockIdx.x*64, kt = blockIdx.y*64;
    if (nt >= N || kt >= K) return;
    const int t = threadIdx.x;
    const int c = t & 63, r0 = t >> 6;
    #pragma unroll 4
    for (int rr=r0; rr<64; rr+=4)
        tile[rr][c] = f2bf(src[(size_t)(kt+rr)*N + nt + c]);
    __syncthreads();
    #pragma unroll 4
    for (int rr=r0; rr<64; rr+=4)
        dst[(size_t)(nt+rr)*K + kt + c] = tile[c][rr];
}

// ---- K/V transpose: kT/vT[b][d][j] from qkvg ------------------------------
__global__ __launch_bounds__(256) void kvtrans(const float* __restrict__ qkvg,
                                               float* __restrict__ kT,
                                               float* __restrict__ vT){
    __shared__ float tile[64][65];
    const int t = threadIdx.x;
    const int jt = blockIdx.x*64, dt = blockIdx.y*64, b = blockIdx.z;
    const int c = t & 63, r0 = t >> 6;
    #pragma unroll 4
    for (int rr=r0; rr<64; rr+=4)
        tile[rr][c] = qkvg[(size_t)((b<<10)+jt+rr)*1024 + 256 + dt + c];
    __syncthreads();
    #pragma unroll 4
    for (int rr=r0; rr<64; rr+=4)
        kT[((size_t)(b*256 + dt + rr))*1024 + jt + c] = tile[c][rr];
    __syncthreads();
    #pragma unroll 4
    for (int rr=r0; rr<64; rr+=4)
        tile[rr][c] = qkvg[(size_t)((b<<10)+jt+rr)*1024 + 512 + dt + c];
    __syncthreads();
    #pragma unroll 4
    for (int rr=r0; rr<64; rr+=4)
        vT[((size_t)(b*256 + dt + rr))*1024 + jt + c] = tile[c][rr];
}

// ---- MFMA bf16 GEMM ------------------------------------------------------
template<int MODE>
__global__ __launch_bounds__(256) void mfma_gemm(
    const unsigned short* __restrict__ A, int lda,
    const unsigned short* __restrict__ Bt, int ldbt,
    float* __restrict__ C, int ldc,
    int K,
    const float* __restrict__ resid,
    const float* __restrict__ mask,
    const float* __restrict__ gsrc,
    const int* __restrict__ idxp)
{
    __shared__ unsigned short As[64*40];
    __shared__ unsigned short Bs[64*40];
    const int t = threadIdx.x;
    const int lane = t & 63, wave = t >> 6;
    const int wr = wave >> 1, wc = wave & 1;
    const int bm = blockIdx.x*64, bn = blockIdx.y*64;
    const int srow = t >> 2, sk = (t & 3) * 8;
    const int l15 = lane & 15, lk = (lane >> 4) * 8;
    f32x4 acc[2][2] = {};
    for (int kt = 0; kt < K; kt += 32){
        *(uint4*)&As[srow*40 + sk] = *(const uint4*)&A [(size_t)(bm+srow)*lda  + kt + sk];
        *(uint4*)&Bs[srow*40 + sk] = *(const uint4*)&Bt[(size_t)(bn+srow)*ldbt + kt + sk];
        __syncthreads();
        bf16x8 a0 = *(const bf16x8*)&As[(32*wr +  0 + l15)*40 + lk];
        bf16x8 a1 = *(const bf16x8*)&As[(32*wr + 16 + l15)*40 + lk];
        bf16x8 b0 = *(const bf16x8*)&Bs[(32*wc +  0 + l15)*40 + lk];
        bf16x8 b1 = *(const bf16x8*)&Bs[(32*wc + 16 + l15)*40 + lk];
        acc[0][0] = __builtin_amdgcn_mfma_f32_16x16x32_bf16(a0,b0,acc[0][0],0,0,0);
        acc[0][1] = __builtin_amdgcn_mfma_f32_16x16x32_bf16(a0,b1,acc[0][1],0,0,0);
        acc[1][0] = __builtin_amdgcn_mfma_f32_16x16x32_bf16(a1,b0,acc[1][0],0,0,0);
        acc[1][1] = __builtin_amdgcn_mfma_f32_16x16x32_bf16(a1,b1,acc[1][1],0,0,0);
        __syncthreads();
    }
    const int rbase = (lane >> 4) * 4;
    #pragma unroll
    for (int m=0;m<2;++m){
        #pragma unroll
        for (int r=0;r<4;++r){
            const int grow = bm + 32*wr + 16*m + rbase + r;
            #pragma unroll
            for (int n=0;n<2;++n){
                const int gcol = bn + 32*wc + 16*n + l15;
                float v = acc[m][n][r];
                if (MODE==0){
                    C[(size_t)grow*ldc + gcol] = v;
                } else if (MODE==1){
                    const float mi = mask[grow];
                    C[(size_t)grow*ldc + gcol] = resid[(size_t)grow*256 + gcol] + v*mi;
                } else {
                    const float mi = mask[grow];
                    const int id = idxp[grow];
                    const int bbi = grow >> 10;
                    const float cg = gsrc[((size_t)(bbi*256+id))*256 + gcol]*mi;
                    C[(size_t)grow*ldc + gcol] = resid[(size_t)grow*256 + gcol] + sigm(cg)*v*mi;
                }
            }
        }
    }
}

// ---- MFMA dual: bmid(bf16) = silu(A@W1) * (A@W2) ---------------------------
__global__ __launch_bounds__(256) void mfma_dual(
    const unsigned short* __restrict__ A, int lda,
    const unsigned short* __restrict__ B1t,
    const unsigned short* __restrict__ B2t, int ldbt,
    unsigned short* __restrict__ C, int ldc,
    int K)
{
    __shared__ unsigned short As[64*40];
    __shared__ unsigned short B1s[64*40];
    __shared__ unsigned short B2s[64*40];
    const int t = threadIdx.x;
    const int lane = t & 63, wave = t >> 6;
    const int wr = wave >> 1, wc = wave & 1;
    const int bm = blockIdx.x*64, bn = blockIdx.y*64;
    const int srow = t >> 2, sk = (t & 3) * 8;
    const int l15 = lane & 15, lk = (lane >> 4) * 8;
    f32x4 acc1[2][2] = {};
    f32x4 acc2[2][2] = {};
    for (int kt = 0; kt < K; kt += 32){
        *(uint4*)&As [srow*40 + sk] = *(const uint4*)&A  [(size_t)(bm+srow)*lda  + kt + sk];
        *(uint4*)&B1s[srow*40 + sk] = *(const uint4*)&B1t[(size_t)(bn+srow)*ldbt + kt + sk];
        *(uint4*)&B2s[srow*40 + sk] = *(const uint4*)&B2t[(size_t)(bn+srow)*ldbt + kt + sk];
        __syncthreads();
        bf16x8 a0 = *(const bf16x8*)&As[(32*wr +  0 + l15)*40 + lk];
        bf16x8 a1 = *(const bf16x8*)&As[(32*wr + 16 + l15)*40 + lk];
        bf16x8 p0 = *(const bf16x8*)&B1s[(32*wc +  0 + l15)*40 + lk];
        bf16x8 p1 = *(const bf16x8*)&B1s[(32*wc + 16 + l15)*40 + lk];
        bf16x8 q0 = *(const bf16x8*)&B2s[(32*wc +  0 + l15)*40 + lk];
        bf16x8 q1 = *(const bf16x8*)&B2s[(32*wc + 16 + l15)*40 + lk];
        acc1[0][0] = __builtin_amdgcn_mfma_f32_16x16x32_bf16(a0,p0,acc1[0][0],0,0,0);
        acc1[0][1] = __builtin_amdgcn_mfma_f32_16x16x32_bf16(a0,p1,acc1[0][1],0,0,0);
        acc1[1][0] = __builtin_amdgcn_mfma_f32_16x16x32_bf16(a1,p0,acc1[1][0],0,0,0);
        acc1[1][1] = __builtin_amdgcn_mfma_f32_16x16x32_bf16(a1,p1,acc1[1][1],0,0,0);
        acc2[0][0] = __builtin_amdgcn_mfma_f32_16x16x32_bf16(a0,q0,acc2[0][0],0,0,0);
        acc2[0][1] = __builtin_amdgcn_mfma_f32_16x16x32_bf16(a0,q1,acc2[0][1],0,0,0);
        acc2[1][0] = __builtin_amdgcn_mfma_f32_16x16x32_bf16(a1,q0,acc2[1][0],0,0,0);
        acc2[1][1] = __builtin_amdgcn_mfma_f32_16x16x32_bf16(a1,q1,acc2[1][1],0,0,0);
        __syncthreads();
    }
    const int rbase = (lane >> 4) * 4;
    #pragma unroll
    for (int m=0;m<2;++m){
        #pragma unroll
        for (int r=0;r<4;++r){
            const int grow = bm + 32*wr + 16*m + rbase + r;
            #pragma unroll
            for (int n=0;n<2;++n){
                const int gcol = bn + 32*wc + 16*n + l15;
                const float u1 = acc1[m][n][r];
                C[(size_t)grow*ldc + gcol] = f2bf(u1*sigm(u1)*acc2[m][n][r]);
            }
        }
    }
}

// ---- 3 small conditioning GEMMs fused into one launch (z selects) ---------
__global__ __launch_bounds__(256) void gemm3(
    const float* __restrict__ cn, const float* __restrict__ s_,
    const float* __restrict__ Wc1, const float* __restrict__ Wcn,
    const float* __restrict__ Wc2,
    const float* __restrict__ bc1, const float* __restrict__ bc2,
    float* __restrict__ c1res, float* __restrict__ cbres,
    float* __restrict__ cgres)
{
    const int z = blockIdx.z;
    const float* A    = (z==2) ? s_  : cn;
    const float* B    = (z==0) ? Wc1 : (z==1) ? Wcn : Wc2;
    const float* bias = (z==0) ? bc1 : (z==2) ? bc2 : nullptr;
    float* C          = (z==0) ? c1res : (z==1) ? cbres : cgres;
    const int lda = 384, ldb = 256, ldc = 256, K = 384;
    __shared__ float As[16][68];
    __shared__ float Bs[16][68];
    const int t = threadIdx.x;
    const int tx = t & 15, ty = t >> 4;
    const int bm = blockIdx.x * 64, bn = blockIdx.y * 64;
    const int am = t >> 2, akq = (t & 3) * 4;
    const int bk = t >> 4, bnq = (t & 15) * 4;
    float acc[4][4] = {};
    for (int kt = 0; kt < K; kt += 16) {
        const float4 va = *(const float4*)&A[(size_t)(bm+am)*lda + kt + akq];
        const float4 vb = *(const float4*)&B[(size_t)(kt+bk)*ldb + bn + bnq];
        As[akq+0][am]=va.x; As[akq+1][am]=va.y; As[akq+2][am]=va.z; As[akq+3][am]=va.w;
        *(float4*)&Bs[bk][bnq] = vb;
        __syncthreads();
        #pragma unroll
        for (int kk=0; kk<16; ++kk){
            const float4 af = *(const float4*)&As[kk][ty*4];
            const float4 bf = *(const float4*)&Bs[kk][tx*4];
            acc[0][0]+=af.x*bf.x; acc[0][1]+=af.x*bf.y; acc[0][2]+=af.x*bf.z; acc[0][3]+=af.x*bf.w;
            acc[1][0]+=af.y*bf.x; acc[1][1]+=af.y*bf.y; acc[1][2]+=af.y*bf.z; acc[1][3]+=af.y*bf.w;
            acc[2][0]+=af.z*bf.x; acc[2][1]+=af.z*bf.y; acc[2][2]+=af.z*bf.z; acc[2][3]+=af.z*bf.w;
            acc[3][0]+=af.w*bf.x; acc[3][1]+=af.w*bf.y; acc[3][2]+=af.w*bf.z; acc[3][3]+=af.w*bf.w;
        }
        __syncthreads();
    }
    #pragma unroll
    for (int i=0;i<4;++i){
        const int m = bm + ty*4 + i;
        #pragma unroll
        for (int jj=0;jj<4;++jj){
            const int n = bn + tx*4 + jj;
            float v = acc[i][jj];
            if (bias) v += bias[n];
            C[(size_t)m*ldc+n] = v;
        }
    }
}

// ---- pair-bias precompute (bf16 out) --------------------------------------
__global__ __launch_bounds__(256,6) void pb_kernel(
    const float* __restrict__ fp,
    const float* __restrict__ lnzg, const float* __restrict__ lnzb,
    const float* __restrict__ wbias,
    const float* __restrict__ mask,
    unsigned short* __restrict__ pb)
{
    __shared__ unsigned short S[8][1040];
    __shared__ float maskS[1024];
    const int t = threadIdx.x;
    const int bi = blockIdx.x;
    const int b = bi >> 10, i = bi & 1023;
    const int l = t & 15, grp = t >> 4;

    float wg[4], wb_[4];
    fv4 w0[4], w1[4];
    #pragma unroll
    for (int cc=0; cc<4; ++cc){
        const int c = 4*l + cc;
        wg[cc] = lnzg[c]; wb_[cc] = lnzb[c];
        w0[cc] = *(const fv4*)&wbias[c*8];
        w1[cc] = *(const fv4*)&wbias[c*8+4];
    }
    *(fv4*)&maskS[t*4] = ((const fv4*)(mask + (b<<10)))[t];
    __syncthreads();
    const float mi = mask[bi];

    const fv4* fpv = (const fv4*)(fp + (size_t)bi*65536);
    fv4 c0 = fpv[(size_t)grp*16 + l];
    fv4 c1 = fpv[(size_t)(grp+16)*16 + l];
    #pragma unroll 1
    for (int jt=0; jt<1024; jt+=32){
        const fv4 f0=c0, f1=c1;
        if (jt+32 < 1024){
            c0 = fpv[(size_t)(jt+32+grp)*16 + l];
            c1 = fpv[(size_t)(jt+48+grp)*16 + l];
        }
        #pragma unroll
        for (int half=0; half<2; ++half){
            const fv4 f = half ? f1 : f0;
            const int j = jt + 16*half + grp;
            float s1 = f.x+f.y+f.z+f.w;
            float s2 = f.x*f.x+f.y*f.y+f.z*f.z+f.w*f.w;
            #pragma unroll
            for (int m=1;m<16;m<<=1){ s1 += __shfl_xor(s1,m); s2 += __shfl_xor(s2,m); }
            const float mu = s1*(1.f/64.f);
            const float rs = rsqrtf(s2*(1.f/64.f) - mu*mu + 1e-5f);
            float lnv[4];
            lnv[0]=(f.x-mu)*rs*wg[0]+wb_[0];
            lnv[1]=(f.y-mu)*rs*wg[1]+wb_[1];
            lnv[2]=(f.z-mu)*rs*wg[2]+wb_[2];
            lnv[3]=(f.w-mu)*rs*wg[3]+wb_[3];
            float pv[8] = {};
            #pragma unroll
            for (int cc=0;cc<4;++cc){
                pv[0]+=lnv[cc]*w0[cc].x; pv[1]+=lnv[cc]*w0[cc].y;
                pv[2]+=lnv[cc]*w0[cc].z; pv[3]+=lnv[cc]*w0[cc].w;
                pv[4]+=lnv[cc]*w1[cc].x; pv[5]+=lnv[cc]*w1[cc].y;
                pv[6]+=lnv[cc]*w1[cc].z; pv[7]+=lnv[cc]*w1[cc].w;
            }
            {
                const bool b8 = (l & 8);
                #pragma unroll
                for (int k=0;k<4;++k){
                    const float a = b8 ? pv[k] : pv[k+4];
                    const float r = __shfl_xor(a, 8);
                    pv[k] = (b8 ? pv[k+4] : pv[k]) + r;
                }
                const bool b4 = (l & 4);
                #pragma unroll
                for (int k=0;k<2;++k){
                    const float a = b4 ? pv[k] : pv[k+2];
                    const float r = __shfl_xor(a, 4);
                    pv[k] = (b4 ? pv[k+2] : pv[k]) + r;
                }
                const bool b2 = (l & 2);
                {
                    const float a = b2 ? pv[0] : pv[1];
                    const float r = __shfl_xor(a, 2);
                    pv[0] = (b2 ? pv[1] : pv[0]) + r;
                }
                pv[0] += __shfl_xor(pv[0], 1);
            }
            if ((l & 1) == 0){
                const float mterm = (mi*maskS[j]-1.f)*100000.f;
                S[(l>>1)][j] = f2bf(pv[0] + mterm);
            }
        }
    }
    __syncthreads();
    #pragma unroll 1
    for (int k=0;k<8;++k){
        const int j4 = (t & 255) * 4;
        const us4 v = *(const us4*)&S[k][j4];
        *(us4*)&pb[(((size_t)(b*8+k))*1024 + i)*1024 + j4] = v;
    }
}

// ---- attention v3 (R11-verified): 8 rows x 1 head; K/V staged in LDS ------
__global__ __launch_bounds__(256,3) void attn_tile(
    const float* __restrict__ qkvg,
    const float* __restrict__ kT,
    const float* __restrict__ vT,
    const unsigned short* __restrict__ pb,
    unsigned short* __restrict__ og)
{
    __shared__ float S[8][1032];
    __shared__ float KV[32][132];
    __shared__ float qs[8][33];
    __shared__ float denomS[8];
    const int t = threadIdx.x;
    const int it = blockIdx.x, h = blockIdx.y, b = blockIdx.z;
    const int i0 = it*8;
    const int r = t >> 5, jl = t & 31;
    const int srow = t >> 3, sc0 = t & 7;

    // ---- S init from pb (bf16 -> f32), contiguous 2KB per row -------------
    {
        const unsigned short* pbb = pb + (((size_t)(b*8+h))*1024 + i0)*1024;
        #pragma unroll
        for (int c=0;c<8;++c){
            const int q4 = t*4;
            const us4 v = *(const us4*)&pbb[(size_t)c*1024 + q4];
            S[c][q4+0] = bf2f(v.x);
            S[c][q4+1] = bf2f(v.y);
            S[c][q4+2] = bf2f(v.z);
            S[c][q4+3] = bf2f(v.w);
        }
    }
    qs[r][jl] = qkvg[((size_t)(b*1024 + i0 + r))*1024 + h*32 + jl];

    const float* kbase = kT + ((size_t)b*256 + h*32)*1024 + (size_t)srow*1024;
    const float* vbase = vT + ((size_t)b*256 + h*32)*1024 + (size_t)srow*1024;
    fv4 pf0 = *(const fv4*)&kbase[0*32 + sc0*4];
    fv4 pf1 = *(const fv4*)&kbase[1*32 + sc0*4];
    fv4 pf2 = *(const fv4*)&kbase[2*32 + sc0*4];
    fv4 pf3 = *(const fv4*)&kbase[3*32 + sc0*4];
    __syncthreads();

    float q[32];
    #pragma unroll
    for (int d=0; d<32; ++d) q[d] = qs[r][d];
    const float scale = 0.17677669529663687f;

    // ---- Phase A: QK^T over 8 K-tiles of 128 j ----------------------------
    for (int tile=0; tile<8; ++tile){
        const int jt = tile*128;
        __syncthreads();
        *(fv4*)&KV[srow][0*32 + sc0*4] = pf0;
        *(fv4*)&KV[srow][1*32 + sc0*4] = pf1;
        *(fv4*)&KV[srow][2*32 + sc0*4] = pf2;
        *(fv4*)&KV[srow][3*32 + sc0*4] = pf3;
        if (tile < 7){
            const float* nb = kbase + (tile+1)*128;
            pf0 = *(const fv4*)&nb[0*32 + sc0*4];
            pf1 = *(const fv4*)&nb[1*32 + sc0*4];
            pf2 = *(const fv4*)&nb[2*32 + sc0*4];
            pf3 = *(const fv4*)&nb[3*32 + sc0*4];
        } else {
            pf0 = *(const fv4*)&vbase[0*32 + sc0*4];
            pf1 = *(const fv4*)&vbase[1*32 + sc0*4];
            pf2 = *(const fv4*)&vbase[2*32 + sc0*4];
            pf3 = *(const fv4*)&vbase[3*32 + sc0*4];
        }
        __syncthreads();
        #pragma unroll
        for (int step=0; step<2; ++step){
            const int tj = step*64 + jl*2;
            float a0=0.f, a1=0.f;
            #pragma unroll
            for (int d=0; d<32; ++d){
                const float2 k2 = *(const float2*)&KV[d][tj];
                a0 += q[d]*k2.x; a1 += q[d]*k2.y;
            }
            float2 s2v = *(float2*)&S[r][jt+tj];
            s2v.x += a0*scale; s2v.y += a1*scale;
            *(float2*)&S[r][jt+tj] = s2v;
        }
    }

    // ---- Phase B: per-row softmax (group-local) ---------------------------
    {
        float mx = -3.4e38f;
        for (int jj=jl; jj<1024; jj+=32) mx = fmaxf(mx, S[r][jj]);
        #pragma unroll
        for (int off=16; off>0; off>>=1) mx = fmaxf(mx, __shfl_xor(mx, off, 32));
        float sum = 0.f;
        for (int jj=jl; jj<1024; jj+=32){
            const float e = __expf(S[r][jj]-mx);
            S[r][jj] = e;
            sum += e;
        }
        #pragma unroll
        for (int off=16; off>0; off>>=1) sum += __shfl_xor(sum, off, 32);
        if (jl==0) denomS[r] = sum;
    }

    // ---- Phase C: PV over 8 V-tiles ---------------------------------------
    float acc[32];
    #pragma unroll
    for (int d=0; d<32; ++d) acc[d] = 0.f;
    for (int tile=0; tile<8; ++tile){
        const int jt = tile*128;
        __syncthreads();
        *(fv4*)&KV[srow][0*32 + sc0*4] = pf0;
        *(fv4*)&KV[srow][1*32 + sc0*4] = pf1;
        *(fv4*)&KV[srow][2*32 + sc0*4] = pf2;
        *(fv4*)&KV[srow][3*32 + sc0*4] = pf3;
        if (tile < 7){
            const float* nb = vbase + (tile+1)*128;
            pf0 = *(const fv4*)&nb[0*32 + sc0*4];
            pf1 = *(const fv4*)&nb[1*32 + sc0*4];
            pf2 = *(const fv4*)&nb[2*32 + sc0*4];
            pf3 = *(const fv4*)&nb[3*32 + sc0*4];
        }
        __syncthreads();
        const fv4 p = *(const fv4*)&S[r][jt + jl*4];
        #pragma unroll
        for (int d=0; d<32; ++d){
            const fv4 vv = *(const fv4*)&KV[d][jl*4];
            acc[d] += p.x*vv.x + p.y*vv.y + p.z*vv.z + p.w*vv.w;
        }
    }

    // ---- reduce-scatter across 32 lanes -> lane jl holds o[d=jl] ----------
    {
        const bool c16 = jl & 16;
        #pragma unroll
        for (int k=0;k<16;++k){
            const float a = c16 ? acc[k] : acc[k+16];
            const float rr = __shfl_xor(a, 16);
            acc[k] = (c16 ? acc[k+16] : acc[k]) + rr;
        }
        const bool c8 = jl & 8;
        #pragma unroll
        for (int k=0;k<8;++k){
            const float a = c8 ? acc[k] : acc[k+8];
            const float rr = __shfl_xor(a, 8);
            acc[k] = (c8 ? acc[k+8] : acc[k]) + rr;
        }
        const bool c4 = jl & 4;
        #pragma unroll
        for (int k=0;k<4;++k){
            const float a = c4 ? acc[k] : acc[k+4];
            const float rr = __shfl_xor(a, 4);
            acc[k] = (c4 ? acc[k+4] : acc[k]) + rr;
        }
        const bool c2 = jl & 2;
        #pragma unroll
        for (int k=0;k<2;++k){
            const float a = c2 ? acc[k] : acc[k+2];
            const float rr = __shfl_xor(a, 2);
            acc[k] = (c2 ? acc[k+2] : acc[k]) + rr;
        }
        const bool c1 = jl & 1;
        {
            const float a = c1 ? acc[0] : acc[1];
            const float rr = __shfl_xor(a, 1);
            acc[0] = (c1 ? acc[1] : acc[0]) + rr;
        }
    }
    const int row = b*1024 + i0 + r;
    const float gpre = qkvg[(size_t)row*1024 + 768 + h*32 + jl];
    og[(size_t)row*256 + h*32 + jl] = f2bf((acc[0]/denomS[r]) * sigm(gpre));
}

// ---- sa = LN(rig)*sigmoid(cond_gate) + cond_bias  (bf16 out) --------------
__global__ __launch_bounds__(256) void sa_kernel(
    const float* __restrict__ rig,
    const float* __restrict__ c1res,
    const float* __restrict__ cbres,
    const int* __restrict__ idxp,
    const float* __restrict__ mask,
    unsigned short* __restrict__ sa)
{
    __shared__ float red[16];
    const int m = blockIdx.x;
    const int t = threadIdx.x;
    const float v = rig[(size_t)m*256 + t];
    float s1 = v, s2 = v*v;
    blockReduce2(s1,s2,red);
    const float mu = s1*(1.f/256.f);
    const float rs = rsqrtf(s2*(1.f/256.f) - mu*mu + 1e-5f);
    const float sn = (v-mu)*rs;
    const float mi = mask[m];
    const int id = idxp[m];
    const int b = m >> 10;
    const size_t go = ((size_t)(b*256+id))*256 + t;
    const float cgate = c1res[go]*mi;
    const float cb    = cbres[go]*mi;
    sa[(size_t)m*256+t] = f2bf(sn*sigm(cgate) + cb);
}

extern "C" void kernel_launch(void* const* d_in, const int* in_sizes, int n_in,
                              void* d_out, int out_size, void* d_ws, size_t ws_size,
                              hipStream_t stream)
{
    (void)in_sizes; (void)n_in; (void)out_size; (void)ws_size;
    const float* s_     = (const float*)d_in[0];
    const float* rigids = (const float*)d_in[1];
    const float* fp     = (const float*)d_in[2];
    const float* maskp  = (const float*)d_in[3];
    const int*   idxp   = (const int*)d_in[4];
    const float* ln_g   = (const float*)d_in[5];
    const float* ln_b   = (const float*)d_in[6];
    const float* Wq     = (const float*)d_in[7];
    const float* Wkv    = (const float*)d_in[8];
    const float* lnz_g  = (const float*)d_in[9];
    const float* lnz_b  = (const float*)d_in[10];
    const float* Wbias  = (const float*)d_in[11];
    const float* Wg     = (const float*)d_in[12];
    const float* Wo     = (const float*)d_in[13];
    const float* lncond = (const float*)d_in[14];
    const float* Wc1    = (const float*)d_in[15];
    const float* bc1    = (const float*)d_in[16];
    const float* Wcn    = (const float*)d_in[17];
    const float* W1     = (const float*)d_in[18];
    const float* W2     = (const float*)d_in[19];
    const float* Wc2    = (const float*)d_in[20];
    const float* bc2    = (const float*)d_in[21];
    const float* Wb     = (const float*)d_in[22];
    float* out = (float*)d_out;

    float* ws    = (float*)d_ws;
    float* qkvg  = ws;                  // 2048*1024 f32
    float* rig   = qkvg  + 2097152;     // 2048*256
    float* cn    = rig   + 524288;      // 512*384
    float* c1res = cn    + 196608;      // 512*256
    float* cbres = c1res + 131072;      // 512*256
    float* cgres = cbres + 131072;      // 512*256
    float* kT    = cgres + 131072;      // 2*256*1024
    float* vT    = kT    + 524288;      // 2*256*1024
    float* bend  = vT    + 524288;
    unsigned short* xbf    = (unsigned short*)bend;        // 2048*256
    unsigned short* ogbf   = xbf    + 524288;              // 2048*256
    unsigned short* sabf   = ogbf   + 524288;              // 2048*256
    unsigned short* bmidbf = sabf   + 524288;              // 2048*512
    unsigned short* wcatT  = bmidbf + 1048576;             // 1024*256
    unsigned short* WoT    = wcatT  + 262144;              // 256*256
    unsigned short* W1T    = WoT    + 65536;               // 512*256
    unsigned short* W2T    = W1T    + 131072;              // 512*256
    unsigned short* WbT    = W2T    + 131072;              // 256*512
    unsigned short* pbbf   = WbT    + 131072;              // 32 MB bf16

    pb_kernel<<<2048,256,0,stream>>>(fp, lnz_g, lnz_b, Wbias, maskp, pbbf);
    cast_all<<<dim3(8,8,7),256,0,stream>>>(Wq, Wkv, Wg, Wo, W1, W2, Wb,
                                           wcatT, WoT, W1T, W2T, WbT);
    ln_rows_bf<<<2048,256,0,stream>>>(rigids, ln_g, ln_b, xbf);
    mfma_gemm<0><<<dim3(32,16),256,0,stream>>>(xbf,256, wcatT,256, qkvg,1024, 256, nullptr,nullptr,nullptr,nullptr);
    kvtrans<<<dim3(16,4,2),256,0,stream>>>(qkvg, kT, vT);
    attn_tile<<<dim3(128,8,2),256,0,stream>>>(qkvg, kT, vT, pbbf, ogbf);
    mfma_gemm<1><<<dim3(32,4),256,0,stream>>>(ogbf,256, WoT,256, rig,256, 256, rigids, maskp, nullptr,nullptr);
    ln_rows<<<512,256,0,stream>>>(s_, lncond, nullptr, cn, 384);
    gemm3<<<dim3(8,4,3),256,0,stream>>>(cn, s_, Wc1, Wcn, Wc2, bc1, bc2, c1res, cbres, cgres);
    sa_kernel<<<2048,256,0,stream>>>(rig, c1res, cbres, idxp, maskp, sabf);
    mfma_dual<<<dim3(32,8),256,0,stream>>>(sabf,256, W1T, W2T,256, bmidbf,512, 256);
    mfma_gemm<2><<<dim3(32,4),256,0,stream>>>(bmidbf,512, WbT,512, out,256, 512, rig, maskp, cgres, idxp);
}

// Round 14
// 244.116 us; speedup vs baseline: 4.2457x; 1.1849x over previous
//
#include <hip/hip_runtime.h>
#include <math.h>

#define DEVI __device__ __forceinline__
typedef float fv4 __attribute__((ext_vector_type(4)));
typedef float f32x4 __attribute__((ext_vector_type(4)));
typedef short bf16x8 __attribute__((ext_vector_type(8)));
typedef unsigned short us4 __attribute__((ext_vector_type(4)));

DEVI float sigm(float x){ return 1.f/(1.f+__expf(-x)); }
DEVI unsigned short f2bf(float f){
    unsigned int u = __float_as_uint(f);
    u = (u + 0x7FFFu + ((u >> 16) & 1u)) >> 16;
    return (unsigned short)u;
}
DEVI float bf2f(unsigned short u){ return __uint_as_float(((unsigned int)u)<<16); }

// ---- block-wide (256 thr) reduction of two sums --------------------------
DEVI void blockReduce2(float& s1, float& s2, float* red){
    #pragma unroll
    for (int m=1;m<64;m<<=1){ s1+=__shfl_xor(s1,m); s2+=__shfl_xor(s2,m); }
    const int w = threadIdx.x>>6;
    if ((threadIdx.x&63)==0){ red[w]=s1; red[8+w]=s2; }
    __syncthreads();
    s1 = red[0]+red[1]+red[2]+red[3];
    s2 = red[8]+red[9]+red[10]+red[11];
}

// ---- generic row LayerNorm (f32 out) -------------------------------------
__global__ __launch_bounds__(256) void ln_rows(const float* __restrict__ in,
                                               const float* __restrict__ g,
                                               const float* __restrict__ bt,
                                               float* __restrict__ out, int C){
    __shared__ float red[16];
    const size_t row = blockIdx.x;
    const float* x = in + row*(size_t)C;
    float s1=0.f, s2=0.f;
    for (int c=threadIdx.x; c<C; c+=256){ float v=x[c]; s1+=v; s2+=v*v; }
    blockReduce2(s1,s2,red);
    const float inv = 1.f/(float)C;
    const float mu = s1*inv;
    const float rs = rsqrtf(s2*inv - mu*mu + 1e-5f);
    float* o = out + row*(size_t)C;
    for (int c=threadIdx.x; c<C; c+=256){
        float y = (x[c]-mu)*rs;
        if (g)  y *= g[c];
        if (bt) y += bt[c];
        o[c] = y;
    }
}

// ---- LayerNorm with bf16 output (C=256) -----------------------------------
__global__ __launch_bounds__(256) void ln_rows_bf(const float* __restrict__ in,
                                                  const float* __restrict__ g,
                                                  const float* __restrict__ bt,
                                                  unsigned short* __restrict__ out){
    __shared__ float red[16];
    const size_t row = blockIdx.x;
    const int t = threadIdx.x;
    const float v = in[row*256 + t];
    float s1=v, s2=v*v;
    blockReduce2(s1,s2,red);
    const float mu = s1*(1.f/256.f);
    const float rs = rsqrtf(s2*(1.f/256.f) - mu*mu + 1e-5f);
    out[row*256 + t] = f2bf((v-mu)*rs*g[t] + bt[t]);
}

// ---- all weight casts+transposes in ONE launch ---------------------------
__global__ __launch_bounds__(256) void cast_all(
    const float* __restrict__ Wq, const float* __restrict__ Wkv,
    const float* __restrict__ Wg, const float* __restrict__ Wo,
    const float* __restrict__ W1, const float* __restrict__ W2,
    const float* __restrict__ Wb,
    unsigned short* __restrict__ wcatT, unsigned short* __restrict__ WoT,
    unsigned short* __restrict__ W1T, unsigned short* __restrict__ W2T,
    unsigned short* __restrict__ WbT)
{
    __shared__ unsigned short tile[64][65];
    const int z = blockIdx.z;
    const float* src; unsigned short* dst; int K, N;
    switch(z){
      case 0: src=Wq;  dst=wcatT;           K=256; N=256; break;
      case 1: src=Wkv; dst=wcatT+256*256;   K=256; N=512; break;
      case 2: src=Wg;  dst=wcatT+768*256;   K=256; N=256; break;
      case 3: src=Wo;  dst=WoT;             K=256; N=256; break;
      case 4: src=W1;  dst=W1T;             K=256; N=512; break;
      case 5: src=W2;  dst=W2T;             K=256; N=512; break;
      default: src=Wb; dst=WbT;             K=512; N=256; break;
    }
    const int nt = blockIdx.x*64, kt = blockIdx.y*64;
    if (nt >= N || kt >= K) return;
    const int t = threadIdx.x;
    const int c = t & 63, r0 = t >> 6;
    #pragma unroll 4
    for (int rr=r0; rr<64; rr+=4)
        tile[rr][c] = f2bf(src[(size_t)(kt+rr)*N + nt + c]);
    __syncthreads();
    #pragma unroll 4
    for (int rr=r0; rr<64; rr+=4)
        dst[(size_t)(nt+rr)*K + kt + c] = tile[c][rr];
}

// ---- V transpose (bf16): vTb[b][dglob][j] from qkvbf cols 512..767 --------
__global__ __launch_bounds__(256) void vtrans(const unsigned short* __restrict__ qkvbf,
                                              unsigned short* __restrict__ vTb){
    __shared__ unsigned short tile[64][65];
    const int t = threadIdx.x;
    const int jt = blockIdx.x*64, dt = blockIdx.y*64, bz = blockIdx.z;
    const int c = t & 63, r0 = t >> 6;
    #pragma unroll 4
    for (int rr=r0; rr<64; rr+=4)
        tile[rr][c] = qkvbf[(size_t)((bz<<10)+jt+rr)*1024 + 512 + dt + c];
    __syncthreads();
    #pragma unroll 4
    for (int rr=r0; rr<64; rr+=4)
        vTb[((size_t)(bz*256 + dt + rr))*1024 + jt + c] = tile[c][rr];
}

// ---- MFMA bf16 GEMM, f32 out (MODE 1: resid+mask, MODE 2: final gate) -----
template<int MODE>
__global__ __launch_bounds__(256) void mfma_gemm(
    const unsigned short* __restrict__ A, int lda,
    const unsigned short* __restrict__ Bt, int ldbt,
    float* __restrict__ C, int ldc,
    int K,
    const float* __restrict__ resid,
    const float* __restrict__ mask,
    const float* __restrict__ gsrc,
    const int* __restrict__ idxp)
{
    __shared__ unsigned short As[64*40];
    __shared__ unsigned short Bs[64*40];
    const int t = threadIdx.x;
    const int lane = t & 63, wave = t >> 6;
    const int wr = wave >> 1, wc = wave & 1;
    const int bm = blockIdx.x*64, bn = blockIdx.y*64;
    const int srow = t >> 2, sk = (t & 3) * 8;
    const int l15 = lane & 15, lk = (lane >> 4) * 8;
    f32x4 acc[2][2] = {};
    for (int kt = 0; kt < K; kt += 32){
        *(uint4*)&As[srow*40 + sk] = *(const uint4*)&A [(size_t)(bm+srow)*lda  + kt + sk];
        *(uint4*)&Bs[srow*40 + sk] = *(const uint4*)&Bt[(size_t)(bn+srow)*ldbt + kt + sk];
        __syncthreads();
        bf16x8 a0 = *(const bf16x8*)&As[(32*wr +  0 + l15)*40 + lk];
        bf16x8 a1 = *(const bf16x8*)&As[(32*wr + 16 + l15)*40 + lk];
        bf16x8 b0 = *(const bf16x8*)&Bs[(32*wc +  0 + l15)*40 + lk];
        bf16x8 b1 = *(const bf16x8*)&Bs[(32*wc + 16 + l15)*40 + lk];
        acc[0][0] = __builtin_amdgcn_mfma_f32_16x16x32_bf16(a0,b0,acc[0][0],0,0,0);
        acc[0][1] = __builtin_amdgcn_mfma_f32_16x16x32_bf16(a0,b1,acc[0][1],0,0,0);
        acc[1][0] = __builtin_amdgcn_mfma_f32_16x16x32_bf16(a1,b0,acc[1][0],0,0,0);
        acc[1][1] = __builtin_amdgcn_mfma_f32_16x16x32_bf16(a1,b1,acc[1][1],0,0,0);
        __syncthreads();
    }
    const int rbase = (lane >> 4) * 4;
    #pragma unroll
    for (int m=0;m<2;++m){
        #pragma unroll
        for (int r=0;r<4;++r){
            const int grow = bm + 32*wr + 16*m + rbase + r;
            #pragma unroll
            for (int n=0;n<2;++n){
                const int gcol = bn + 32*wc + 16*n + l15;
                float v = acc[m][n][r];
                if (MODE==1){
                    const float mi = mask[grow];
                    C[(size_t)grow*ldc + gcol] = resid[(size_t)grow*256 + gcol] + v*mi;
                } else {
                    const float mi = mask[grow];
                    const int id = idxp[grow];
                    const int bbi = grow >> 10;
                    const float cg = gsrc[((size_t)(bbi*256+id))*256 + gcol]*mi;
                    C[(size_t)grow*ldc + gcol] = resid[(size_t)grow*256 + gcol] + sigm(cg)*v*mi;
                }
            }
        }
    }
}

// ---- MFMA bf16 GEMM with bf16 output (plain) -------------------------------
__global__ __launch_bounds__(256) void mfma_gemm_bfout(
    const unsigned short* __restrict__ A, int lda,
    const unsigned short* __restrict__ Bt, int ldbt,
    unsigned short* __restrict__ C, int ldc,
    int K)
{
    __shared__ unsigned short As[64*40];
    __shared__ unsigned short Bs[64*40];
    const int t = threadIdx.x;
    const int lane = t & 63, wave = t >> 6;
    const int wr = wave >> 1, wc = wave & 1;
    const int bm = blockIdx.x*64, bn = blockIdx.y*64;
    const int srow = t >> 2, sk = (t & 3) * 8;
    const int l15 = lane & 15, lk = (lane >> 4) * 8;
    f32x4 acc[2][2] = {};
    for (int kt = 0; kt < K; kt += 32){
        *(uint4*)&As[srow*40 + sk] = *(const uint4*)&A [(size_t)(bm+srow)*lda  + kt + sk];
        *(uint4*)&Bs[srow*40 + sk] = *(const uint4*)&Bt[(size_t)(bn+srow)*ldbt + kt + sk];
        __syncthreads();
        bf16x8 a0 = *(const bf16x8*)&As[(32*wr +  0 + l15)*40 + lk];
        bf16x8 a1 = *(const bf16x8*)&As[(32*wr + 16 + l15)*40 + lk];
        bf16x8 b0 = *(const bf16x8*)&Bs[(32*wc +  0 + l15)*40 + lk];
        bf16x8 b1 = *(const bf16x8*)&Bs[(32*wc + 16 + l15)*40 + lk];
        acc[0][0] = __builtin_amdgcn_mfma_f32_16x16x32_bf16(a0,b0,acc[0][0],0,0,0);
        acc[0][1] = __builtin_amdgcn_mfma_f32_16x16x32_bf16(a0,b1,acc[0][1],0,0,0);
        acc[1][0] = __builtin_amdgcn_mfma_f32_16x16x32_bf16(a1,b0,acc[1][0],0,0,0);
        acc[1][1] = __builtin_amdgcn_mfma_f32_16x16x32_bf16(a1,b1,acc[1][1],0,0,0);
        __syncthreads();
    }
    const int rbase = (lane >> 4) * 4;
    #pragma unroll
    for (int m=0;m<2;++m){
        #pragma unroll
        for (int r=0;r<4;++r){
            const int grow = bm + 32*wr + 16*m + rbase + r;
            #pragma unroll
            for (int n=0;n<2;++n){
                const int gcol = bn + 32*wc + 16*n + l15;
                C[(size_t)grow*ldc + gcol] = f2bf(acc[m][n][r]);
            }
        }
    }
}

// ---- MFMA dual: bmid(bf16) = silu(A@W1) * (A@W2) ---------------------------
__global__ __launch_bounds__(256) void mfma_dual(
    const unsigned short* __restrict__ A, int lda,
    const unsigned short* __restrict__ B1t,
    const unsigned short* __restrict__ B2t, int ldbt,
    unsigned short* __restrict__ C, int ldc,
    int K)
{
    __shared__ unsigned short As[64*40];
    __shared__ unsigned short B1s[64*40];
    __shared__ unsigned short B2s[64*40];
    const int t = threadIdx.x;
    const int lane = t & 63, wave = t >> 6;
    const int wr = wave >> 1, wc = wave & 1;
    const int bm = blockIdx.x*64, bn = blockIdx.y*64;
    const int srow = t >> 2, sk = (t & 3) * 8;
    const int l15 = lane & 15, lk = (lane >> 4) * 8;
    f32x4 acc1[2][2] = {};
    f32x4 acc2[2][2] = {};
    for (int kt = 0; kt < K; kt += 32){
        *(uint4*)&As [srow*40 + sk] = *(const uint4*)&A  [(size_t)(bm+srow)*lda  + kt + sk];
        *(uint4*)&B1s[srow*40 + sk] = *(const uint4*)&B1t[(size_t)(bn+srow)*ldbt + kt + sk];
        *(uint4*)&B2s[srow*40 + sk] = *(const uint4*)&B2t[(size_t)(bn+srow)*ldbt + kt + sk];
        __syncthreads();
        bf16x8 a0 = *(const bf16x8*)&As[(32*wr +  0 + l15)*40 + lk];
        bf16x8 a1 = *(const bf16x8*)&As[(32*wr + 16 + l15)*40 + lk];
        bf16x8 p0 = *(const bf16x8*)&B1s[(32*wc +  0 + l15)*40 + lk];
        bf16x8 p1 = *(const bf16x8*)&B1s[(32*wc + 16 + l15)*40 + lk];
        bf16x8 q0 = *(const bf16x8*)&B2s[(32*wc +  0 + l15)*40 + lk];
        bf16x8 q1 = *(const bf16x8*)&B2s[(32*wc + 16 + l15)*40 + lk];
        acc1[0][0] = __builtin_amdgcn_mfma_f32_16x16x32_bf16(a0,p0,acc1[0][0],0,0,0);
        acc1[0][1] = __builtin_amdgcn_mfma_f32_16x16x32_bf16(a0,p1,acc1[0][1],0,0,0);
        acc1[1][0] = __builtin_amdgcn_mfma_f32_16x16x32_bf16(a1,p0,acc1[1][0],0,0,0);
        acc1[1][1] = __builtin_amdgcn_mfma_f32_16x16x32_bf16(a1,p1,acc1[1][1],0,0,0);
        acc2[0][0] = __builtin_amdgcn_mfma_f32_16x16x32_bf16(a0,q0,acc2[0][0],0,0,0);
        acc2[0][1] = __builtin_amdgcn_mfma_f32_16x16x32_bf16(a0,q1,acc2[0][1],0,0,0);
        acc2[1][0] = __builtin_amdgcn_mfma_f32_16x16x32_bf16(a1,q0,acc2[1][0],0,0,0);
        acc2[1][1] = __builtin_amdgcn_mfma_f32_16x16x32_bf16(a1,q1,acc2[1][1],0,0,0);
        __syncthreads();
    }
    const int rbase = (lane >> 4) * 4;
    #pragma unroll
    for (int m=0;m<2;++m){
        #pragma unroll
        for (int r=0;r<4;++r){
            const int grow = bm + 32*wr + 16*m + rbase + r;
            #pragma unroll
            for (int n=0;n<2;++n){
                const int gcol = bn + 32*wc + 16*n + l15;
                const float u1 = acc1[m][n][r];
                C[(size_t)grow*ldc + gcol] = f2bf(u1*sigm(u1)*acc2[m][n][r]);
            }
        }
    }
}

// ---- S = Q@K^T * scale + pb   (in-place into pb buffer, bf16) --------------
// grid (i-tile 16, j-tile 16, bh 16). Single K step (K=32).
__global__ __launch_bounds__(256) void s_gemm(
    const unsigned short* __restrict__ qkvbf,
    unsigned short* __restrict__ Sb)
{
    __shared__ unsigned short As[64*40];
    __shared__ unsigned short Bs[64*40];
    const int t = threadIdx.x;
    const int lane = t & 63, wave = t >> 6;
    const int wr = wave >> 1, wc = wave & 1;
    const int bm = blockIdx.x*64, bn = blockIdx.y*64;
    const int bh = blockIdx.z, b = bh >> 3, h = bh & 7;
    const int srow = t >> 2, sk = (t & 3) * 8;
    const int l15 = lane & 15, lk = (lane >> 4) * 8;
    const unsigned short* Aq = qkvbf + (size_t)b*1024*1024 + h*32;
    const unsigned short* Bk = qkvbf + (size_t)b*1024*1024 + 256 + h*32;
    *(uint4*)&As[srow*40 + sk] = *(const uint4*)&Aq[(size_t)(bm+srow)*1024 + sk];
    *(uint4*)&Bs[srow*40 + sk] = *(const uint4*)&Bk[(size_t)(bn+srow)*1024 + sk];
    __syncthreads();
    bf16x8 a0 = *(const bf16x8*)&As[(32*wr +  0 + l15)*40 + lk];
    bf16x8 a1 = *(const bf16x8*)&As[(32*wr + 16 + l15)*40 + lk];
    bf16x8 b0 = *(const bf16x8*)&Bs[(32*wc +  0 + l15)*40 + lk];
    bf16x8 b1 = *(const bf16x8*)&Bs[(32*wc + 16 + l15)*40 + lk];
    f32x4 acc[2][2] = {};
    acc[0][0] = __builtin_amdgcn_mfma_f32_16x16x32_bf16(a0,b0,acc[0][0],0,0,0);
    acc[0][1] = __builtin_amdgcn_mfma_f32_16x16x32_bf16(a0,b1,acc[0][1],0,0,0);
    acc[1][0] = __builtin_amdgcn_mfma_f32_16x16x32_bf16(a1,b0,acc[1][0],0,0,0);
    acc[1][1] = __builtin_amdgcn_mfma_f32_16x16x32_bf16(a1,b1,acc[1][1],0,0,0);
    const float scale = 0.17677669529663687f;
    const int rbase = (lane >> 4) * 4;
    #pragma unroll
    for (int m=0;m<2;++m){
        #pragma unroll
        for (int r=0;r<4;++r){
            const int grow = bm + 32*wr + 16*m + rbase + r;
            #pragma unroll
            for (int n=0;n<2;++n){
                const int gcol = bn + 32*wc + 16*n + l15;
                const size_t idx = ((size_t)bh*1024 + grow)*1024 + gcol;
                Sb[idx] = f2bf(acc[m][n][r]*scale + bf2f(Sb[idx]));
            }
        }
    }
}

// ---- row softmax in place (bf16), one row (1024) per block ----------------
__global__ __launch_bounds__(256) void softmax_rows(unsigned short* __restrict__ S){
    __shared__ float red[16];
    const int t = threadIdx.x;
    unsigned short* base = S + (size_t)blockIdx.x*1024;
    const us4 v = *(const us4*)&base[t*4];
    float f0=bf2f(v.x), f1=bf2f(v.y), f2=bf2f(v.z), f3=bf2f(v.w);
    float m = fmaxf(fmaxf(f0,f1), fmaxf(f2,f3));
    #pragma unroll
    for (int o=1;o<64;o<<=1) m = fmaxf(m, __shfl_xor(m,o));
    const int w = t>>6;
    if ((t&63)==0) red[w] = m;
    __syncthreads();
    m = fmaxf(fmaxf(red[0],red[1]), fmaxf(red[2],red[3]));
    f0=__expf(f0-m); f1=__expf(f1-m); f2=__expf(f2-m); f3=__expf(f3-m);
    float s = f0+f1+f2+f3;
    #pragma unroll
    for (int o=1;o<64;o<<=1) s += __shfl_xor(s,o);
    if ((t&63)==0) red[8+w] = s;
    __syncthreads();
    const float inv = 1.f/(red[8]+red[9]+red[10]+red[11]);
    us4 o4;
    o4.x=f2bf(f0*inv); o4.y=f2bf(f1*inv); o4.z=f2bf(f2*inv); o4.w=f2bf(f3*inv);
    *(us4*)&base[t*4] = o4;
}

// ---- O = P @ V, gated epilogue. grid (i-tile 16, 1, bh 16). ----------------
// M=64 (4 waves stacked), N=32 (2 frags), K=1024. Register-prefetched staging.
__global__ __launch_bounds__(256) void pv_gemm(
    const unsigned short* __restrict__ P,
    const unsigned short* __restrict__ vTb,
    const unsigned short* __restrict__ qkvbf,
    unsigned short* __restrict__ og)
{
    __shared__ unsigned short As[64*40];
    __shared__ unsigned short Bs[32*40];
    const int t = threadIdx.x;
    const int lane = t & 63, wave = t >> 6;
    const int bm = blockIdx.x*64;
    const int bh = blockIdx.z, b = bh >> 3, h = bh & 7;
    const int l15 = lane & 15, lk = (lane >> 4) * 8;
    const unsigned short* Pb = P   + ((size_t)bh*1024)*1024;
    const unsigned short* Vb = vTb + ((size_t)(b*256 + h*32))*1024;
    const int srow = t >> 2, sk = (t & 3) * 8;
    uint4 pfA = *(const uint4*)&Pb[(size_t)(bm+srow)*1024 + sk];
    uint4 pfB;
    if (t < 128) pfB = *(const uint4*)&Vb[(size_t)srow*1024 + sk];
    f32x4 acc0 = {}, acc1 = {};
    for (int kt = 0; kt < 1024; kt += 32){
        __syncthreads();                      // prev tile consumed
        *(uint4*)&As[srow*40 + sk] = pfA;
        if (t < 128) *(uint4*)&Bs[srow*40 + sk] = pfB;
        if (kt + 32 < 1024){
            pfA = *(const uint4*)&Pb[(size_t)(bm+srow)*1024 + kt + 32 + sk];
            if (t < 128) pfB = *(const uint4*)&Vb[(size_t)srow*1024 + kt + 32 + sk];
        }
        __syncthreads();                      // tile ready
        bf16x8 a  = *(const bf16x8*)&As[(16*wave + l15)*40 + lk];
        bf16x8 b0 = *(const bf16x8*)&Bs[( 0 + l15)*40 + lk];
        bf16x8 b1 = *(const bf16x8*)&Bs[(16 + l15)*40 + lk];
        acc0 = __builtin_amdgcn_mfma_f32_16x16x32_bf16(a,b0,acc0,0,0,0);
        acc1 = __builtin_amdgcn_mfma_f32_16x16x32_bf16(a,b1,acc1,0,0,0);
    }
    const int rbase = (lane >> 4) * 4;
    #pragma unroll
    for (int r=0;r<4;++r){
        const int irow = bm + 16*wave + rbase + r;
        const size_t grow = (size_t)b*1024 + irow;
        {
            const int d = 0 + l15;
            const float gate = bf2f(qkvbf[grow*1024 + 768 + h*32 + d]);
            og[grow*256 + h*32 + d] = f2bf(acc0[r]*sigm(gate));
        }
        {
            const int d = 16 + l15;
            const float gate = bf2f(qkvbf[grow*1024 + 768 + h*32 + d]);
            og[grow*256 + h*32 + d] = f2bf(acc1[r]*sigm(gate));
        }
    }
}

// ---- 3 small conditioning GEMMs fused into one launch (z selects) ---------
__global__ __launch_bounds__(256) void gemm3(
    const float* __restrict__ cn, const float* __restrict__ s_,
    const float* __restrict__ Wc1, const float* __restrict__ Wcn,
    const float* __restrict__ Wc2,
    const float* __restrict__ bc1, const float* __restrict__ bc2,
    float* __restrict__ c1res, float* __restrict__ cbres,
    float* __restrict__ cgres)
{
    const int z = blockIdx.z;
    const float* A    = (z==2) ? s_  : cn;
    const float* B    = (z==0) ? Wc1 : (z==1) ? Wcn : Wc2;
    const float* bias = (z==0) ? bc1 : (z==2) ? bc2 : nullptr;
    float* C          = (z==0) ? c1res : (z==1) ? cbres : cgres;
    const int lda = 384, ldb = 256, ldc = 256, K = 384;
    __shared__ float As[16][68];
    __shared__ float Bs[16][68];
    const int t = threadIdx.x;
    const int tx = t & 15, ty = t >> 4;
    const int bm = blockIdx.x * 64, bn = blockIdx.y * 64;
    const int am = t >> 2, akq = (t & 3) * 4;
    const int bk = t >> 4, bnq = (t & 15) * 4;
    float acc[4][4] = {};
    for (int kt = 0; kt < K; kt += 16) {
        const float4 va = *(const float4*)&A[(size_t)(bm+am)*lda + kt + akq];
        const float4 vb = *(const float4*)&B[(size_t)(kt+bk)*ldb + bn + bnq];
        As[akq+0][am]=va.x; As[akq+1][am]=va.y; As[akq+2][am]=va.z; As[akq+3][am]=va.w;
        *(float4*)&Bs[bk][bnq] = vb;
        __syncthreads();
        #pragma unroll
        for (int kk=0; kk<16; ++kk){
            const float4 af = *(const float4*)&As[kk][ty*4];
            const float4 bf = *(const float4*)&Bs[kk][tx*4];
            acc[0][0]+=af.x*bf.x; acc[0][1]+=af.x*bf.y; acc[0][2]+=af.x*bf.z; acc[0][3]+=af.x*bf.w;
            acc[1][0]+=af.y*bf.x; acc[1][1]+=af.y*bf.y; acc[1][2]+=af.y*bf.z; acc[1][3]+=af.y*bf.w;
            acc[2][0]+=af.z*bf.x; acc[2][1]+=af.z*bf.y; acc[2][2]+=af.z*bf.z; acc[2][3]+=af.z*bf.w;
            acc[3][0]+=af.w*bf.x; acc[3][1]+=af.w*bf.y; acc[3][2]+=af.w*bf.z; acc[3][3]+=af.w*bf.w;
        }
        __syncthreads();
    }
    #pragma unroll
    for (int i=0;i<4;++i){
        const int m = bm + ty*4 + i;
        #pragma unroll
        for (int jj=0;jj<4;++jj){
            const int n = bn + tx*4 + jj;
            float v = acc[i][jj];
            if (bias) v += bias[n];
            C[(size_t)m*ldc+n] = v;
        }
    }
}

// ---- pair-bias precompute (bf16 out) --------------------------------------
__global__ __launch_bounds__(256,6) void pb_kernel(
    const float* __restrict__ fp,
    const float* __restrict__ lnzg, const float* __restrict__ lnzb,
    const float* __restrict__ wbias,
    const float* __restrict__ mask,
    unsigned short* __restrict__ pb)
{
    __shared__ unsigned short S[8][1040];
    __shared__ float maskS[1024];
    const int t = threadIdx.x;
    const int bi = blockIdx.x;
    const int b = bi >> 10, i = bi & 1023;
    const int l = t & 15, grp = t >> 4;

    float wg[4], wb_[4];
    fv4 w0[4], w1[4];
    #pragma unroll
    for (int cc=0; cc<4; ++cc){
        const int c = 4*l + cc;
        wg[cc] = lnzg[c]; wb_[cc] = lnzb[c];
        w0[cc] = *(const fv4*)&wbias[c*8];
        w1[cc] = *(const fv4*)&wbias[c*8+4];
    }
    *(fv4*)&maskS[t*4] = ((const fv4*)(mask + (b<<10)))[t];
    __syncthreads();
    const float mi = mask[bi];

    const fv4* fpv = (const fv4*)(fp + (size_t)bi*65536);
    fv4 c0 = fpv[(size_t)grp*16 + l];
    fv4 c1 = fpv[(size_t)(grp+16)*16 + l];
    #pragma unroll 1
    for (int jt=0; jt<1024; jt+=32){
        const fv4 f0=c0, f1=c1;
        if (jt+32 < 1024){
            c0 = fpv[(size_t)(jt+32+grp)*16 + l];
            c1 = fpv[(size_t)(jt+48+grp)*16 + l];
        }
        #pragma unroll
        for (int half=0; half<2; ++half){
            const fv4 f = half ? f1 : f0;
            const int j = jt + 16*half + grp;
            float s1 = f.x+f.y+f.z+f.w;
            float s2 = f.x*f.x+f.y*f.y+f.z*f.z+f.w*f.w;
            #pragma unroll
            for (int m=1;m<16;m<<=1){ s1 += __shfl_xor(s1,m); s2 += __shfl_xor(s2,m); }
            const float mu = s1*(1.f/64.f);
            const float rs = rsqrtf(s2*(1.f/64.f) - mu*mu + 1e-5f);
            float lnv[4];
            lnv[0]=(f.x-mu)*rs*wg[0]+wb_[0];
            lnv[1]=(f.y-mu)*rs*wg[1]+wb_[1];
            lnv[2]=(f.z-mu)*rs*wg[2]+wb_[2];
            lnv[3]=(f.w-mu)*rs*wg[3]+wb_[3];
            float pv[8] = {};
            #pragma unroll
            for (int cc=0;cc<4;++cc){
                pv[0]+=lnv[cc]*w0[cc].x; pv[1]+=lnv[cc]*w0[cc].y;
                pv[2]+=lnv[cc]*w0[cc].z; pv[3]+=lnv[cc]*w0[cc].w;
                pv[4]+=lnv[cc]*w1[cc].x; pv[5]+=lnv[cc]*w1[cc].y;
                pv[6]+=lnv[cc]*w1[cc].z; pv[7]+=lnv[cc]*w1[cc].w;
            }
            {
                const bool b8 = (l & 8);
                #pragma unroll
                for (int k=0;k<4;++k){
                    const float a = b8 ? pv[k] : pv[k+4];
                    const float r = __shfl_xor(a, 8);
                    pv[k] = (b8 ? pv[k+4] : pv[k]) + r;
                }
                const bool b4 = (l & 4);
                #pragma unroll
                for (int k=0;k<2;++k){
                    const float a = b4 ? pv[k] : pv[k+2];
                    const float r = __shfl_xor(a, 4);
                    pv[k] = (b4 ? pv[k+2] : pv[k]) + r;
                }
                const bool b2 = (l & 2);
                {
                    const float a = b2 ? pv[0] : pv[1];
                    const float r = __shfl_xor(a, 2);
                    pv[0] = (b2 ? pv[1] : pv[0]) + r;
                }
                pv[0] += __shfl_xor(pv[0], 1);
            }
            if ((l & 1) == 0){
                const float mterm = (mi*maskS[j]-1.f)*100000.f;
                S[(l>>1)][j] = f2bf(pv[0] + mterm);
            }
        }
    }
    __syncthreads();
    #pragma unroll 1
    for (int k=0;k<8;++k){
        const int j4 = (t & 255) * 4;
        const us4 v = *(const us4*)&S[k][j4];
        *(us4*)&pb[(((size_t)(b*8+k))*1024 + i)*1024 + j4] = v;
    }
}

// ---- sa = LN(rig)*sigmoid(cond_gate) + cond_bias  (bf16 out) --------------
__global__ __launch_bounds__(256) void sa_kernel(
    const float* __restrict__ rig,
    const float* __restrict__ c1res,
    const float* __restrict__ cbres,
    const int* __restrict__ idxp,
    const float* __restrict__ mask,
    unsigned short* __restrict__ sa)
{
    __shared__ float red[16];
    const int m = blockIdx.x;
    const int t = threadIdx.x;
    const float v = rig[(size_t)m*256 + t];
    float s1 = v, s2 = v*v;
    blockReduce2(s1,s2,red);
    const float mu = s1*(1.f/256.f);
    const float rs = rsqrtf(s2*(1.f/256.f) - mu*mu + 1e-5f);
    const float sn = (v-mu)*rs;
    const float mi = mask[m];
    const int id = idxp[m];
    const int b = m >> 10;
    const size_t go = ((size_t)(b*256+id))*256 + t;
    const float cgate = c1res[go]*mi;
    const float cb    = cbres[go]*mi;
    sa[(size_t)m*256+t] = f2bf(sn*sigm(cgate) + cb);
}

extern "C" void kernel_launch(void* const* d_in, const int* in_sizes, int n_in,
                              void* d_out, int out_size, void* d_ws, size_t ws_size,
                              hipStream_t stream)
{
    (void)in_sizes; (void)n_in; (void)out_size; (void)ws_size;
    const float* s_     = (const float*)d_in[0];
    const float* rigids = (const float*)d_in[1];
    const float* fp     = (const float*)d_in[2];
    const float* maskp  = (const float*)d_in[3];
    const int*   idxp   = (const int*)d_in[4];
    const float* ln_g   = (const float*)d_in[5];
    const float* ln_b   = (const float*)d_in[6];
    const float* Wq     = (const float*)d_in[7];
    const float* Wkv    = (const float*)d_in[8];
    const float* lnz_g  = (const float*)d_in[9];
    const float* lnz_b  = (const float*)d_in[10];
    const float* Wbias  = (const float*)d_in[11];
    const float* Wg     = (const float*)d_in[12];
    const float* Wo     = (const float*)d_in[13];
    const float* lncond = (const float*)d_in[14];
    const float* Wc1    = (const float*)d_in[15];
    const float* bc1    = (const float*)d_in[16];
    const float* Wcn    = (const float*)d_in[17];
    const float* W1     = (const float*)d_in[18];
    const float* W2     = (const float*)d_in[19];
    const float* Wc2    = (const float*)d_in[20];
    const float* bc2    = (const float*)d_in[21];
    const float* Wb     = (const float*)d_in[22];
    float* out = (float*)d_out;

    float* ws    = (float*)d_ws;
    float* rig   = ws;                  // 2048*256 f32
    float* cn    = rig   + 524288;      // 512*384
    float* c1res = cn    + 196608;      // 512*256
    float* cbres = c1res + 131072;      // 512*256
    float* cgres = cbres + 131072;      // 512*256
    float* bend  = cgres + 131072;
    unsigned short* xbf    = (unsigned short*)bend;        // 2048*256
    unsigned short* ogbf   = xbf    + 524288;              // 2048*256
    unsigned short* sabf   = ogbf   + 524288;              // 2048*256
    unsigned short* bmidbf = sabf   + 524288;              // 2048*512
    unsigned short* wcatT  = bmidbf + 1048576;             // 1024*256
    unsigned short* WoT    = wcatT  + 262144;              // 256*256
    unsigned short* W1T    = WoT    + 65536;               // 512*256
    unsigned short* W2T    = W1T    + 131072;              // 512*256
    unsigned short* WbT    = W2T    + 131072;              // 256*512
    unsigned short* qkvbf  = WbT    + 131072;              // 2048*1024 bf16
    unsigned short* vTb    = qkvbf  + 2097152;             // 2*256*1024 bf16
    unsigned short* pbbf   = vTb    + 524288;              // 16*1024*1024 bf16 (pb -> S -> P)

    pb_kernel<<<2048,256,0,stream>>>(fp, lnz_g, lnz_b, Wbias, maskp, pbbf);
    cast_all<<<dim3(8,8,7),256,0,stream>>>(Wq, Wkv, Wg, Wo, W1, W2, Wb,
                                           wcatT, WoT, W1T, W2T, WbT);
    ln_rows_bf<<<2048,256,0,stream>>>(rigids, ln_g, ln_b, xbf);
    mfma_gemm_bfout<<<dim3(32,16),256,0,stream>>>(xbf,256, wcatT,256, qkvbf,1024, 256);
    vtrans<<<dim3(16,4,2),256,0,stream>>>(qkvbf, vTb);
    s_gemm<<<dim3(16,16,16),256,0,stream>>>(qkvbf, pbbf);
    softmax_rows<<<16384,256,0,stream>>>(pbbf);
    pv_gemm<<<dim3(16,1,16),256,0,stream>>>(pbbf, vTb, qkvbf, ogbf);
    mfma_gemm<1><<<dim3(32,4),256,0,stream>>>(ogbf,256, WoT,256, rig,256, 256, rigids, maskp, nullptr,nullptr);
    ln_rows<<<512,256,0,stream>>>(s_, lncond, nullptr, cn, 384);
    gemm3<<<dim3(8,4,3),256,0,stream>>>(cn, s_, Wc1, Wcn, Wc2, bc1, bc2, c1res, cbres, cgres);
    sa_kernel<<<2048,256,0,stream>>>(rig, c1res, cbres, idxp, maskp, sabf);
    mfma_dual<<<dim3(32,8),256,0,stream>>>(sabf,256, W1T, W2T,256, bmidbf,512, 256);
    mfma_gemm<2><<<dim3(32,4),256,0,stream>>>(bmidbf,512, WbT,512, out,256, 512, rig, maskp, cgres, idxp);
}